// Round 3
// baseline (1278.428 us; speedup 1.0000x reference)
//
#include <hip/hip_runtime.h>
#include <hip/hip_bf16.h>
#include <hip/hip_fp16.h>

#define N_Q 10000
#define D_MODEL 256
#define NH 8
#define PT 4
#define PP 4
#define PS 4
#define DFF 1024
#define NC 6
#define HF 24
#define WF 60
#define BH 100
#define BW 100
#define T_RAD 0.15f
#define S_RAD 0.12f

typedef __hip_bfloat16 bf16;

__device__ __forceinline__ float b2f(bf16 v) { return __bfloat162float(v); }
__device__ __forceinline__ bf16 f2b(float v) { return __float2bfloat16(v); }

// dtype-adaptive loads/stores; f: 0=f32, 1=bf16, 2=f16
__device__ __forceinline__ float load_any(const void* p, long i, int f) {
    if (f == 0) return ((const float*)p)[i];
    if (f == 1) return b2f(((const bf16*)p)[i]);
    return __half2float(((const __half*)p)[i]);
}
__device__ __forceinline__ void store_any(void* p, long i, int f, float v) {
    if (f == 0)      ((float*)p)[i] = v;
    else if (f == 1) ((bf16*)p)[i] = f2b(v);
    else             ((__half*)p)[i] = __float2half(v);
}

// ---------------- dtype / mask-width detection ----------------
// flags[0]: float dtype (0=f32,1=bf16,2=f16). flags[1]: mask element bytes.
__global__ void detect_kernel(const void* __restrict__ ln1g, const void* __restrict__ mask,
                              int* __restrict__ flags) {
    if (blockIdx.x != 0 || threadIdx.x != 0) return;
    unsigned short u0 = ((const unsigned short*)ln1g)[0];
    flags[0] = (u0 == 0x3F80) ? 1 : (u0 == 0x3C00 ? 2 : 0);

    const unsigned long long* m64 = (const unsigned long long*)mask;
    const unsigned int*       m32 = (const unsigned int*)mask;
    const unsigned short*     m16 = (const unsigned short*)mask;
    bool ok8 = true, ok4 = true, ok2 = true;
    int ones8 = 0, ones4 = 0, ones2 = 0;
    for (int i = 0; i < 120; i++) {
        unsigned long long v = m64[i];
        if (v == 1ULL) ones8++; else if (v != 0ULL) ok8 = false;
    }
    for (int i = 0; i < 240; i++) {
        unsigned int v = m32[i];
        if (v == 1u || v == 0x3F800000u) ones4++; else if (v != 0u) ok4 = false;
    }
    for (int i = 0; i < 480; i++) {
        unsigned short v = m16[i];
        if (v == 1 || v == 0x3F80) ones2++; else if (v != 0) ok2 = false;
    }
    int ms;
    if (ok8 && ones8 > 30)       ms = 8;
    else if (ok4 && ones4 > 60)  ms = 4;
    else if (ok2 && ones2 > 120) ms = 2;
    else                         ms = 1;
    flags[1] = ms;
}

// ---------------- batched weight conversion -> bf16 canonical ----------------
#define NW 22
struct WCvt {
    const void* src[NW];
    int dst_off[NW];
    int count[NW];
    int blk_start[NW + 1];
};
__global__ __launch_bounds__(256) void cvt_w_kernel(WCvt wc, bf16* __restrict__ dst,
                                                    const int* __restrict__ flags) {
    int blk = blockIdx.x;
    int a = 0;
    while (a < NW - 1 && blk >= wc.blk_start[a + 1]) a++;
    int i = (blk - wc.blk_start[a]) * 256 + threadIdx.x;
    if (i >= wc.count[a]) return;
    dst[wc.dst_off[a] + i] = f2b(load_any(wc.src[a], i, flags[0]));
}

// ---------------- image_feats (c, ch, y, x) -> imgT (c, y, x, ch) bf16 ----------------
__global__ __launch_bounds__(256) void transpose_img(const void* __restrict__ in,
                                                     bf16* __restrict__ out,
                                                     const int* __restrict__ flags) {
    int i = blockIdx.x * 256 + threadIdx.x;
    if (i >= NC * HF * WF * 256) return;
    int ch = i & 255;
    int t = i >> 8;
    int xx = t % WF; t /= WF;
    int yy = t % HF;
    int c  = t / HF;
    long src = (((long)(c * 256) + ch) * HF + yy) * WF + xx;
    out[i] = f2b(load_any(in, src, flags[0]));
}

// ---------------- LayerNorm over D=256, one row per block -> bf16 out ----------------
// kind: 0 = f32 pointer (ws), 1 = raw input via flags
__global__ __launch_bounds__(256) void ln_kernel(const void* __restrict__ in, int kind,
                                                 const int* __restrict__ flags,
                                                 const bf16* __restrict__ g,
                                                 const bf16* __restrict__ b,
                                                 bf16* __restrict__ out, int ostride, int ooff) {
    int n = blockIdx.x, tid = threadIdx.x;
    float v = kind ? load_any(in, (long)n * D_MODEL + tid, flags[0])
                   : ((const float*)in)[(long)n * D_MODEL + tid];
    __shared__ float red[D_MODEL];
    red[tid] = v; __syncthreads();
    #pragma unroll
    for (int s = 128; s > 0; s >>= 1) { if (tid < s) red[tid] += red[tid + s]; __syncthreads(); }
    float mu = red[0] * (1.f / D_MODEL); __syncthreads();
    float d = v - mu;
    red[tid] = d * d; __syncthreads();
    #pragma unroll
    for (int s = 128; s > 0; s >>= 1) { if (tid < s) red[tid] += red[tid + s]; __syncthreads(); }
    float var = red[0] * (1.f / D_MODEL);
    out[(long)n * ostride + ooff + tid] = f2b(d * rsqrtf(var + 1e-5f) * b2f(g[tid]) + b2f(b[tid]));
}

// ---------------- GEMM: [M,K](bf16) @ [K,J](bf16) + bias ----------------
// mode 0: ->bf16 out; 1: tanh*scale ->bf16; 2: + raw residual ->f32; 3: + f32 residual ->f32
template <int K, int J, int TM>
__global__ __launch_bounds__(J) void gemm_kernel(const bf16* __restrict__ A, int lda,
                                                 const bf16* __restrict__ W,
                                                 const bf16* __restrict__ bias,
                                                 int mode, float scale,
                                                 bf16* __restrict__ outb, float* outf, int ldo,
                                                 const void* __restrict__ resraw,
                                                 const float* resf,
                                                 const int* __restrict__ flags) {
    constexpr int KC = 64;
    __shared__ __align__(16) float As[KC][TM];
    int j = threadIdx.x;
    int row0 = blockIdx.x * TM;
    float acc[TM];
    #pragma unroll
    for (int r = 0; r < TM; r++) acc[r] = 0.f;
    for (int k0 = 0; k0 < K; k0 += KC) {
        __syncthreads();
        for (int t = j; t < TM * (KC / 8); t += J) {
            int r = t >> 3, seg = t & 7;
            uint4 u = *reinterpret_cast<const uint4*>(A + (size_t)(row0 + r) * lda + k0 + seg * 8);
            int kk = seg * 8;
            As[kk + 0][r] = __uint_as_float(u.x << 16);
            As[kk + 1][r] = __uint_as_float(u.x & 0xFFFF0000u);
            As[kk + 2][r] = __uint_as_float(u.y << 16);
            As[kk + 3][r] = __uint_as_float(u.y & 0xFFFF0000u);
            As[kk + 4][r] = __uint_as_float(u.z << 16);
            As[kk + 5][r] = __uint_as_float(u.z & 0xFFFF0000u);
            As[kk + 6][r] = __uint_as_float(u.w << 16);
            As[kk + 7][r] = __uint_as_float(u.w & 0xFFFF0000u);
        }
        __syncthreads();
        #pragma unroll 8
        for (int kk = 0; kk < KC; kk++) {
            float w = b2f(W[(size_t)(k0 + kk) * J + j]);
            const float4* ap = reinterpret_cast<const float4*>(&As[kk][0]);
            #pragma unroll
            for (int r4 = 0; r4 < TM / 4; r4++) {
                float4 a = ap[r4];
                acc[r4 * 4 + 0] += a.x * w;
                acc[r4 * 4 + 1] += a.y * w;
                acc[r4 * 4 + 2] += a.z * w;
                acc[r4 * 4 + 3] += a.w * w;
            }
        }
    }
    float bb = b2f(bias[j]);
    #pragma unroll
    for (int r = 0; r < TM; r++) {
        long o = (long)(row0 + r) * ldo + j;
        float v = acc[r] + bb;
        if (mode == 0)      outb[o] = f2b(v);
        else if (mode == 1) outb[o] = f2b(tanhf(v) * scale);
        else if (mode == 2) outf[o] = v + load_any(resraw, o, flags[0]);
        else                outf[o] = v + resf[o];
    }
}

// ---------------- Temporal deformable sampling ----------------
// ai: [N,512] bf16 = [pb | q1]; acts as maps (d,100,100) with n = y*100+x
__global__ __launch_bounds__(256) void temporal_kernel(const bf16* __restrict__ ai,
                                                       const bf16* __restrict__ toffB,
                                                       const bf16* __restrict__ twlB,
                                                       const void* __restrict__ ref2d,
                                                       const void* __restrict__ ego,
                                                       const int* __restrict__ flags,
                                                       bf16* __restrict__ tfB) {
    int n = blockIdx.x, tid = threadIdx.x;
    int g = tid >> 5, hd = tid & 31;
    __shared__ float s_toff[128];
    __shared__ float s_twl[64];
    __shared__ float s_base[4];
    if (tid < 128) s_toff[tid] = b2f(toffB[(long)n * 128 + tid]);
    if (tid >= 128 && tid < 192) s_twl[tid - 128] = b2f(twlB[(long)n * 64 + tid - 128]);
    if (tid == 192) {
        int f = flags[0];
        float rx = load_any(ref2d, (long)n * 2, f), ry = load_any(ref2d, (long)n * 2 + 1, f);
        s_base[0] = rx + load_any(ego, 0, f); s_base[1] = ry + load_any(ego, 1, f);
        s_base[2] = rx;                       s_base[3] = ry;
    }
    __syncthreads();
    float total = 0.f;
    #pragma unroll
    for (int si = 0; si < 2; si++) {
        float l0 = s_twl[si * 32 + g * 4 + 0], l1 = s_twl[si * 32 + g * 4 + 1];
        float l2 = s_twl[si * 32 + g * 4 + 2], l3 = s_twl[si * 32 + g * 4 + 3];
        float mx = fmaxf(fmaxf(l0, l1), fmaxf(l2, l3));
        float e0 = __expf(l0 - mx), e1 = __expf(l1 - mx);
        float e2 = __expf(l2 - mx), e3 = __expf(l3 - mx);
        float inv = 1.f / (e0 + e1 + e2 + e3);
        float wts[4] = {e0 * inv, e1 * inv, e2 * inv, e3 * inv};
        int aoff = (si == 0) ? 0 : 256;
        float bx = s_base[si * 2], by = s_base[si * 2 + 1];
        #pragma unroll
        for (int pt = 0; pt < 4; pt++) {
            float u = bx + s_toff[si * 64 + g * 8 + pt * 2 + 0];
            float v = by + s_toff[si * 64 + g * 8 + pt * 2 + 1];
            float ix = u * (float)BW - 0.5f;
            float iy = v * (float)BH - 0.5f;
            float x0f = floorf(ix), y0f = floorf(iy);
            int x0 = (int)x0f, y0 = (int)y0f;
            float wx1 = ix - x0f, wy1 = iy - y0f;
            float wx0 = 1.f - wx1, wy0 = 1.f - wy1;
            float val = 0.f;
            #pragma unroll
            for (int cy = 0; cy < 2; cy++) {
                int yy = y0 + cy;
                if ((unsigned)yy >= BH) continue;
                float wy = cy ? wy1 : wy0;
                #pragma unroll
                for (int cx = 0; cx < 2; cx++) {
                    int xx = x0 + cx;
                    if ((unsigned)xx >= BW) continue;
                    float wxx = cx ? wx1 : wx0;
                    val += wy * wxx * b2f(ai[(long)(yy * BW + xx) * 512 + aoff + g * 32 + hd]);
                }
            }
            total += wts[pt] * val;
        }
    }
    tfB[(long)n * D_MODEL + tid] = f2b(0.5f * total);
}

// ---------------- Spatial cross-attention sampling ----------------
__global__ __launch_bounds__(256) void spatial_kernel(const bf16* __restrict__ soffB,
                                                      const bf16* __restrict__ swlB,
                                                      const void* __restrict__ refcam,
                                                      const void* __restrict__ bmask,
                                                      const bf16* __restrict__ imgT,
                                                      const void* __restrict__ img_raw,
                                                      int use_imgT,
                                                      const int* __restrict__ flags,
                                                      bf16* __restrict__ sfB) {
    int n = blockIdx.x, tid = threadIdx.x;
    int g = tid >> 5, hd = tid & 31;
    __shared__ float s_soff[256];
    __shared__ float s_swl[128];
    __shared__ float s_ref[NC][PP][2];
    __shared__ int s_vis[NC][PP];
    s_soff[tid] = b2f(soffB[(long)n * 256 + tid]);
    if (tid < 128) s_swl[tid] = b2f(swlB[(long)n * 128 + tid]);
    if (tid >= 128 && tid < 128 + 48) {
        int t = tid - 128; int c = t >> 3, r = t & 7;
        s_ref[c][r >> 1][r & 1] =
            load_any(refcam, ((long)(c * N_Q + n) * PP + (r >> 1)) * 2 + (r & 1), flags[0]);
    }
    if (tid >= 192 && tid < 192 + 24) {
        int t = tid - 192; int c = t >> 2, p = t & 3;
        long idx = (long)(c * N_Q + n) * PP + p;
        int msize = flags[1];
        int v;
        if (msize == 1)      v = ((const unsigned char*)bmask)[idx] != 0;
        else if (msize == 2) v = ((const unsigned short*)bmask)[idx] != 0;
        else if (msize == 4) v = ((const unsigned int*)bmask)[idx] != 0u;
        else                 v = ((const unsigned long long*)bmask)[idx] != 0ULL;
        s_vis[c][p] = v;
    }
    __syncthreads();
    int fdt = flags[0];
    float acc = 0.f, cnt = 0.f;
    for (int c = 0; c < NC; c++) {
        if (!(s_vis[c][0] || s_vis[c][1] || s_vis[c][2] || s_vis[c][3])) continue;
        float w[16];
        float mx = -3e38f;
        #pragma unroll
        for (int i = 0; i < 16; i++) {
            int vis = s_vis[c][i >> 2];
            float li = vis ? s_swl[g * 16 + i] : -3e38f;
            w[i] = li;
            mx = fmaxf(mx, li);
        }
        float sum = 0.f;
        #pragma unroll
        for (int i = 0; i < 16; i++) {
            float e = (w[i] > -1e37f) ? __expf(w[i] - mx) : 0.f;
            w[i] = e; sum += e;
        }
        float inv = 1.f / sum;
        const bf16* img = imgT + (size_t)c * HF * WF * 256;
        float vacc = 0.f;
        #pragma unroll
        for (int p = 0; p < PP; p++) {
            if (!s_vis[c][p]) continue;
            float rx = s_ref[c][p][0], ry = s_ref[c][p][1];
            #pragma unroll
            for (int s = 0; s < PS; s++) {
                float wi = w[p * 4 + s] * inv;
                float u = rx + s_soff[g * 32 + p * 8 + s * 2 + 0];
                float v = ry + s_soff[g * 32 + p * 8 + s * 2 + 1];
                float ix = u * (float)WF - 0.5f, iy = v * (float)HF - 0.5f;
                float x0f = floorf(ix), y0f = floorf(iy);
                int x0 = (int)x0f, y0 = (int)y0f;
                float wx1 = ix - x0f, wy1 = iy - y0f;
                float wx0 = 1.f - wx1, wy0 = 1.f - wy1;
                float val = 0.f;
                #pragma unroll
                for (int cy = 0; cy < 2; cy++) {
                    int yy = y0 + cy;
                    if ((unsigned)yy >= HF) continue;
                    float wy = cy ? wy1 : wy0;
                    #pragma unroll
                    for (int cx = 0; cx < 2; cx++) {
                        int xx = x0 + cx;
                        if ((unsigned)xx >= WF) continue;
                        float wxx = cx ? wx1 : wx0;
                        float fv;
                        if (use_imgT)
                            fv = b2f(img[(long)(yy * WF + xx) * 256 + g * 32 + hd]);
                        else
                            fv = load_any(img_raw,
                                          (((long)c * 256 + g * 32 + hd) * HF + yy) * WF + xx, fdt);
                        val += wy * wxx * fv;
                    }
                }
                vacc += wi * val;
            }
        }
        acc += vacc; cnt += 1.f;
    }
    sfB[(long)n * 256 + tid] = f2b(acc / fmaxf(cnt, 1.f));
}

// ---------------- Fused FFN: LN3 -> @w1+b1, relu -> @w2+b2, + residual -> out (adaptive dtype) ----
#define FTM 4
__global__ __launch_bounds__(256) void ffn_kernel(const float* __restrict__ x,
                                                  const bf16* __restrict__ g3,
                                                  const bf16* __restrict__ b3,
                                                  const bf16* __restrict__ w1,
                                                  const bf16* __restrict__ b1,
                                                  const bf16* __restrict__ w2,
                                                  const bf16* __restrict__ b2v,
                                                  void* __restrict__ out,
                                                  const int* __restrict__ flags) {
    __shared__ __align__(16) float xlT[D_MODEL][FTM];
    __shared__ __align__(16) float hT[DFF][FTM];
    __shared__ float red[256];
    int tid = threadIdx.x;
    int row0 = blockIdx.x * FTM;
    float gg = b2f(g3[tid]), gb = b2f(b3[tid]);
    #pragma unroll
    for (int r = 0; r < FTM; r++) {
        float v = x[(long)(row0 + r) * D_MODEL + tid];
        red[tid] = v; __syncthreads();
        #pragma unroll
        for (int s = 128; s > 0; s >>= 1) { if (tid < s) red[tid] += red[tid + s]; __syncthreads(); }
        float mu = red[0] * (1.f / 256.f); __syncthreads();
        float d = v - mu;
        red[tid] = d * d; __syncthreads();
        #pragma unroll
        for (int s = 128; s > 0; s >>= 1) { if (tid < s) red[tid] += red[tid + s]; __syncthreads(); }
        float var = red[0] * (1.f / 256.f); __syncthreads();
        xlT[tid][r] = d * rsqrtf(var + 1e-5f) * gg + gb;
    }
    __syncthreads();
    #pragma unroll
    for (int q = 0; q < 4; q++) {
        int jj = tid + q * 256;
        float a0 = 0, a1 = 0, a2 = 0, a3 = 0;
        #pragma unroll 4
        for (int k = 0; k < 256; k++) {
            float wv = b2f(w1[(long)k * DFF + jj]);
            const float4 a = *reinterpret_cast<const float4*>(&xlT[k][0]);
            a0 += a.x * wv; a1 += a.y * wv; a2 += a.z * wv; a3 += a.w * wv;
        }
        float bb = b2f(b1[jj]);
        hT[jj][0] = fmaxf(a0 + bb, 0.f);
        hT[jj][1] = fmaxf(a1 + bb, 0.f);
        hT[jj][2] = fmaxf(a2 + bb, 0.f);
        hT[jj][3] = fmaxf(a3 + bb, 0.f);
    }
    __syncthreads();
    float a0 = 0, a1 = 0, a2 = 0, a3 = 0;
    #pragma unroll 4
    for (int k = 0; k < DFF; k++) {
        float wv = b2f(w2[(long)k * D_MODEL + tid]);
        const float4 a = *reinterpret_cast<const float4*>(&hT[k][0]);
        a0 += a.x * wv; a1 += a.y * wv; a2 += a.z * wv; a3 += a.w * wv;
    }
    float bb = b2f(b2v[tid]);
    int f = flags[0];
    store_any(out, (long)(row0 + 0) * D_MODEL + tid, f, x[(long)(row0 + 0) * D_MODEL + tid] + a0 + bb);
    store_any(out, (long)(row0 + 1) * D_MODEL + tid, f, x[(long)(row0 + 1) * D_MODEL + tid] + a1 + bb);
    store_any(out, (long)(row0 + 2) * D_MODEL + tid, f, x[(long)(row0 + 2) * D_MODEL + tid] + a2 + bb);
    store_any(out, (long)(row0 + 3) * D_MODEL + tid, f, x[(long)(row0 + 3) * D_MODEL + tid] + a3 + bb);
}

// bf16 element offsets inside the weight region
#define W_TOFF_W 0
#define W_TOFF_B 65536
#define W_TWT_W  65664
#define W_TWT_B  98432
#define W_TOUT_W 98496
#define W_TOUT_B 164032
#define W_SOFF_W 164288
#define W_SOFF_B 229824
#define W_SWT_W  230080
#define W_SWT_B  262848
#define W_SOUT_W 262976
#define W_SOUT_B 328512
#define W_FFN_W1 328768
#define W_FFN_B1 590912
#define W_FFN_W2 591936
#define W_FFN_B2 854080
#define W_LN1_G  854336
#define W_LN1_B  854592
#define W_LN2_G  854848
#define W_LN2_B  855104
#define W_LN3_G  855360
#define W_LN3_B  855616

// byte offsets in workspace (total 35,576,320 B)
#define OB_WGT   0
#define OB_FLAGS 1711744
#define OB_AI    1712640
#define OB_TF    11952640
#define OB_X     17072640
#define OB_T4    27312640
#define OB_IMG   31152640
#define WS_NEED_IMG 35576320ULL

extern "C" void kernel_launch(void* const* d_in, const int* in_sizes, int n_in,
                              void* d_out, int out_size, void* d_ws, size_t ws_size,
                              hipStream_t stream) {
    char* W8 = (char*)d_ws;
    bf16*  wgt   = (bf16*)(W8 + OB_WGT);
    int*   flags = (int*)(W8 + OB_FLAGS);
    bf16*  ai    = (bf16*)(W8 + OB_AI);                 // N x 512, pb | q1
    bf16*  q2B   = ai;                                  // N x 256 (after temporal)
    bf16*  sfB   = (bf16*)(W8 + OB_AI + 5120000);       // N x 256
    bf16*  tfB   = (bf16*)(W8 + OB_TF);                 // N x 256
    bf16*  soffB = tfB;                                 // N x 256 (after t_out gemm)
    float* x     = (float*)(W8 + OB_X);                 // N x 256 f32 trunk
    bf16*  toffB = (bf16*)(W8 + OB_T4);                 // N x 128
    bf16*  twlB  = (bf16*)(W8 + OB_T4 + 2560000);       // N x 64
    bf16*  swlB  = toffB;                               // N x 128 (after temporal)
    bf16*  imgT  = (bf16*)(W8 + OB_IMG);                // NC*HF*WF*256
    int use_imgT = (ws_size >= WS_NEED_IMG) ? 1 : 0;

    detect_kernel<<<1, 64, 0, stream>>>(d_in[22] /*ln1_g*/, d_in[28] /*bev_mask*/, flags);

    {
        WCvt wc;
        const int srcs[NW] = {6,7,8,9,10,11,12,13,14,15,16,17,18,19,20,21,22,23,24,25,26,27};
        const int offs[NW] = {W_TOFF_W,W_TOFF_B,W_TWT_W,W_TWT_B,W_TOUT_W,W_TOUT_B,
                              W_SOFF_W,W_SOFF_B,W_SWT_W,W_SWT_B,W_SOUT_W,W_SOUT_B,
                              W_FFN_W1,W_FFN_B1,W_FFN_W2,W_FFN_B2,
                              W_LN1_G,W_LN1_B,W_LN2_G,W_LN2_B,W_LN3_G,W_LN3_B};
        const int cnts[NW] = {65536,128,32768,64,65536,256,65536,256,32768,128,65536,256,
                              262144,1024,262144,256,256,256,256,256,256,256};
        int blk = 0;
        for (int a = 0; a < NW; a++) {
            wc.src[a] = d_in[srcs[a]];
            wc.dst_off[a] = offs[a];
            wc.count[a] = cnts[a];
            wc.blk_start[a] = blk;
            blk += (cnts[a] + 255) / 256;
        }
        wc.blk_start[NW] = blk;
        cvt_w_kernel<<<blk, 256, 0, stream>>>(wc, wgt, flags);
    }

    ln_kernel<<<N_Q, 256, 0, stream>>>(d_in[1], 1, flags, wgt + W_LN1_G, wgt + W_LN1_B, ai, 512, 0);
    ln_kernel<<<N_Q, 256, 0, stream>>>(d_in[0], 1, flags, wgt + W_LN1_G, wgt + W_LN1_B, ai, 512, 256);
    gemm_kernel<512, 128, 16><<<625, 128, 0, stream>>>(ai, 512, wgt + W_TOFF_W, wgt + W_TOFF_B,
        1, T_RAD, toffB, nullptr, 128, nullptr, nullptr, flags);
    gemm_kernel<512, 64, 16><<<625, 64, 0, stream>>>(ai, 512, wgt + W_TWT_W, wgt + W_TWT_B,
        0, 0.f, twlB, nullptr, 64, nullptr, nullptr, flags);
    temporal_kernel<<<N_Q, 256, 0, stream>>>(ai, toffB, twlB, d_in[3], d_in[5], flags, tfB);
    gemm_kernel<256, 256, 16><<<625, 256, 0, stream>>>(tfB, 256, wgt + W_TOUT_W, wgt + W_TOUT_B,
        2, 0.f, nullptr, x, 256, d_in[0], nullptr, flags);
    ln_kernel<<<N_Q, 256, 0, stream>>>(x, 0, flags, wgt + W_LN2_G, wgt + W_LN2_B, q2B, 256, 0);
    gemm_kernel<256, 256, 16><<<625, 256, 0, stream>>>(q2B, 256, wgt + W_SOFF_W, wgt + W_SOFF_B,
        1, S_RAD, soffB, nullptr, 256, nullptr, nullptr, flags);
    gemm_kernel<256, 128, 16><<<625, 128, 0, stream>>>(q2B, 256, wgt + W_SWT_W, wgt + W_SWT_B,
        0, 0.f, swlB, nullptr, 128, nullptr, nullptr, flags);
    if (use_imgT)
        transpose_img<<<8640, 256, 0, stream>>>(d_in[2], imgT, flags);
    spatial_kernel<<<N_Q, 256, 0, stream>>>(soffB, swlB, d_in[4], d_in[28], imgT, d_in[2],
                                            use_imgT, flags, sfB);
    gemm_kernel<256, 256, 16><<<625, 256, 0, stream>>>(sfB, 256, wgt + W_SOUT_W, wgt + W_SOUT_B,
        3, 0.f, nullptr, x, 256, nullptr, x, flags);
    ffn_kernel<<<2500, 256, 0, stream>>>(x, wgt + W_LN3_G, wgt + W_LN3_B,
                                         wgt + W_FFN_W1, wgt + W_FFN_B1,
                                         wgt + W_FFN_W2, wgt + W_FFN_B2, d_out, flags);
}

// Round 4
// 949.920 us; speedup vs baseline: 1.3458x; 1.3458x over previous
//
#include <hip/hip_runtime.h>
#include <hip/hip_bf16.h>
#include <hip/hip_fp16.h>

#define N_Q 10000
#define D_MODEL 256
#define NH 8
#define PT 4
#define PP 4
#define PS 4
#define DFF 1024
#define NC 6
#define HF 24
#define WF 60
#define BH 100
#define BW 100
#define T_RAD 0.15f
#define S_RAD 0.12f

typedef __hip_bfloat16 bf16;

__device__ __forceinline__ float b2f(bf16 v) { return __bfloat162float(v); }
__device__ __forceinline__ bf16 f2b(float v) { return __float2bfloat16(v); }

// dtype-adaptive loads/stores; f: 0=f32, 1=bf16, 2=f16
__device__ __forceinline__ float load_any(const void* p, long i, int f) {
    if (f == 0) return ((const float*)p)[i];
    if (f == 1) return b2f(((const bf16*)p)[i]);
    return __half2float(((const __half*)p)[i]);
}
__device__ __forceinline__ void store_any(void* p, long i, int f, float v) {
    if (f == 0)      ((float*)p)[i] = v;
    else if (f == 1) ((bf16*)p)[i] = f2b(v);
    else             ((__half*)p)[i] = __float2half(v);
}

__device__ __forceinline__ unsigned pack2(float a, float b) {
    bf16 x = f2b(a), y = f2b(b);
    unsigned short ux = *(unsigned short*)&x, uy = *(unsigned short*)&y;
    return (unsigned)ux | ((unsigned)uy << 16);
}

// ---------------- dtype / mask-width detection (parallel) ----------------
// flags[0]: float dtype (0=f32,1=bf16,2=f16). flags[1]: mask element bytes.
__global__ __launch_bounds__(256) void detect_kernel(const void* __restrict__ ln1g,
                                                     const void* __restrict__ mask,
                                                     int* __restrict__ flags) {
    __shared__ int sh[6];  // ok8, ones8, ok4, ones4, ok2, ones2
    int tid = threadIdx.x;
    if (tid < 6) sh[tid] = (tid == 0 || tid == 2 || tid == 4) ? 1 : 0;
    __syncthreads();
    const unsigned long long* m64 = (const unsigned long long*)mask;
    const unsigned int*       m32 = (const unsigned int*)mask;
    const unsigned short*     m16 = (const unsigned short*)mask;
    int lok8 = 1, lones8 = 0, lok4 = 1, lones4 = 0, lok2 = 1, lones2 = 0;
    for (int i = tid; i < 480; i += 256) {
        if (i < 120) {
            unsigned long long v = m64[i];
            if (v == 1ULL) lones8++; else if (v != 0ULL) lok8 = 0;
        }
        if (i < 240) {
            unsigned int v = m32[i];
            if (v == 1u || v == 0x3F800000u) lones4++; else if (v != 0u) lok4 = 0;
        }
        unsigned short v = m16[i];
        if (v == 1 || v == 0x3F80) lones2++; else if (v != 0) lok2 = 0;
    }
    atomicAnd(&sh[0], lok8); atomicAdd(&sh[1], lones8);
    atomicAnd(&sh[2], lok4); atomicAdd(&sh[3], lones4);
    atomicAnd(&sh[4], lok2); atomicAdd(&sh[5], lones2);
    __syncthreads();
    if (tid == 0) {
        unsigned short u0 = ((const unsigned short*)ln1g)[0];
        flags[0] = (u0 == 0x3F80) ? 1 : (u0 == 0x3C00 ? 2 : 0);
        int ms;
        if (sh[0] && sh[1] > 30)       ms = 8;
        else if (sh[2] && sh[3] > 60)  ms = 4;
        else if (sh[4] && sh[5] > 120) ms = 2;
        else                           ms = 1;
        flags[1] = ms;
    }
}

// ---------------- batched weight conversion -> bf16 canonical ----------------
#define NW 22
struct WCvt {
    const void* src[NW];
    int dst_off[NW];
    int count[NW];
    int blk_start[NW + 1];
};
__global__ __launch_bounds__(256) void cvt_w_kernel(WCvt wc, bf16* __restrict__ dst,
                                                    const int* __restrict__ flags) {
    int blk = blockIdx.x;
    int a = 0;
    while (a < NW - 1 && blk >= wc.blk_start[a + 1]) a++;
    int i = (blk - wc.blk_start[a]) * 256 + threadIdx.x;
    if (i >= wc.count[a]) return;
    dst[wc.dst_off[a] + i] = f2b(load_any(wc.src[a], i, flags[0]));
}

// ---------------- image_feats (c, ch, y, x) -> imgT (c, y, x, ch) bf16 ----------------
__global__ __launch_bounds__(256) void transpose_img(const void* __restrict__ in,
                                                     bf16* __restrict__ out,
                                                     const int* __restrict__ flags) {
    int i = blockIdx.x * 256 + threadIdx.x;
    if (i >= NC * HF * WF * 256) return;
    int ch = i & 255;
    int t = i >> 8;
    int xx = t % WF; t /= WF;
    int yy = t % HF;
    int c  = t / HF;
    long src = (((long)(c * 256) + ch) * HF + yy) * WF + xx;
    out[i] = f2b(load_any(in, src, flags[0]));
}

// ---------------- LayerNorm over D=256, one row per block -> bf16 out ----------------
// kind: 0 = f32 pointer (ws), 1 = raw input via flags
__global__ __launch_bounds__(256) void ln_kernel(const void* __restrict__ in, int kind,
                                                 const int* __restrict__ flags,
                                                 const bf16* __restrict__ g,
                                                 const bf16* __restrict__ b,
                                                 bf16* __restrict__ out, int ostride, int ooff) {
    int n = blockIdx.x, tid = threadIdx.x;
    float v = kind ? load_any(in, (long)n * D_MODEL + tid, flags[0])
                   : ((const float*)in)[(long)n * D_MODEL + tid];
    __shared__ float red[D_MODEL];
    red[tid] = v; __syncthreads();
    #pragma unroll
    for (int s = 128; s > 0; s >>= 1) { if (tid < s) red[tid] += red[tid + s]; __syncthreads(); }
    float mu = red[0] * (1.f / D_MODEL); __syncthreads();
    float d = v - mu;
    red[tid] = d * d; __syncthreads();
    #pragma unroll
    for (int s = 128; s > 0; s >>= 1) { if (tid < s) red[tid] += red[tid + s]; __syncthreads(); }
    float var = red[0] * (1.f / D_MODEL);
    out[(long)n * ostride + ooff + tid] = f2b(d * rsqrtf(var + 1e-5f) * b2f(g[tid]) + b2f(b[tid]));
}

// ---------------- GEMM: [M,K](bf16) @ [K,J](bf16) + bias ----------------
// mode 0: ->bf16 out; 1: tanh*scale ->bf16; 2: + raw residual ->f32; 3: + f32 residual ->f32
template <int K, int J, int TM>
__global__ __launch_bounds__(J) void gemm_kernel(const bf16* __restrict__ A, int lda,
                                                 const bf16* __restrict__ W,
                                                 const bf16* __restrict__ bias,
                                                 int mode, float scale,
                                                 bf16* __restrict__ outb, float* outf, int ldo,
                                                 const void* __restrict__ resraw,
                                                 const float* resf,
                                                 const int* __restrict__ flags) {
    constexpr int KC = 64;
    __shared__ __align__(16) float As[KC][TM];
    int j = threadIdx.x;
    int row0 = blockIdx.x * TM;
    float acc[TM];
    #pragma unroll
    for (int r = 0; r < TM; r++) acc[r] = 0.f;
    for (int k0 = 0; k0 < K; k0 += KC) {
        __syncthreads();
        for (int t = j; t < TM * (KC / 8); t += J) {
            int r = t >> 3, seg = t & 7;
            uint4 u = *reinterpret_cast<const uint4*>(A + (size_t)(row0 + r) * lda + k0 + seg * 8);
            int kk = seg * 8;
            As[kk + 0][r] = __uint_as_float(u.x << 16);
            As[kk + 1][r] = __uint_as_float(u.x & 0xFFFF0000u);
            As[kk + 2][r] = __uint_as_float(u.y << 16);
            As[kk + 3][r] = __uint_as_float(u.y & 0xFFFF0000u);
            As[kk + 4][r] = __uint_as_float(u.z << 16);
            As[kk + 5][r] = __uint_as_float(u.z & 0xFFFF0000u);
            As[kk + 6][r] = __uint_as_float(u.w << 16);
            As[kk + 7][r] = __uint_as_float(u.w & 0xFFFF0000u);
        }
        __syncthreads();
        #pragma unroll 8
        for (int kk = 0; kk < KC; kk++) {
            float w = b2f(W[(size_t)(k0 + kk) * J + j]);
            const float4* ap = reinterpret_cast<const float4*>(&As[kk][0]);
            #pragma unroll
            for (int r4 = 0; r4 < TM / 4; r4++) {
                float4 a = ap[r4];
                acc[r4 * 4 + 0] += a.x * w;
                acc[r4 * 4 + 1] += a.y * w;
                acc[r4 * 4 + 2] += a.z * w;
                acc[r4 * 4 + 3] += a.w * w;
            }
        }
    }
    float bb = b2f(bias[j]);
    #pragma unroll
    for (int r = 0; r < TM; r++) {
        long o = (long)(row0 + r) * ldo + j;
        float v = acc[r] + bb;
        if (mode == 0)      outb[o] = f2b(v);
        else if (mode == 1) outb[o] = f2b(tanhf(v) * scale);
        else if (mode == 2) outf[o] = v + load_any(resraw, o, flags[0]);
        else                outf[o] = v + resf[o];
    }
}

// ---------------- Temporal deformable sampling (8 queries/block, 8 ch/thread) ----------------
// ai: [N,512] bf16 = [pb | q1]; acts as maps (d,100,100) with n = y*100+x
__global__ __launch_bounds__(256) void temporal_kernel(const bf16* __restrict__ ai,
                                                       const bf16* __restrict__ toffB,
                                                       const bf16* __restrict__ twlB,
                                                       const void* __restrict__ ref2d,
                                                       const void* __restrict__ ego,
                                                       const int* __restrict__ flags,
                                                       bf16* __restrict__ tfB) {
    int tid = threadIdx.x;
    int ql = tid >> 5, t = tid & 31;
    int g = t >> 2, q4 = t & 3;
    long n0 = (long)blockIdx.x * 8;
    __shared__ float s_toff[8][8][17];  // [q][g][si*8 + pt*2 + e]  (padded)
    __shared__ float s_twl[8][64];
    __shared__ float s_base[8][4];
    for (int i = tid; i < 8 * 128; i += 256) {
        int q = i >> 7, j = i & 127;
        int si = j >> 6, r = j & 63, gg = r >> 3, w = r & 7;
        s_toff[q][gg][si * 8 + w] = b2f(toffB[n0 * 128 + i]);
    }
    for (int i = tid; i < 8 * 64; i += 256) s_twl[i >> 6][i & 63] = b2f(twlB[n0 * 64 + i]);
    if (tid < 8) {
        int f = flags[0];
        float rx = load_any(ref2d, (n0 + tid) * 2, f), ry = load_any(ref2d, (n0 + tid) * 2 + 1, f);
        s_base[tid][0] = rx + load_any(ego, 0, f); s_base[tid][1] = ry + load_any(ego, 1, f);
        s_base[tid][2] = rx;                       s_base[tid][3] = ry;
    }
    __syncthreads();
    float acc[8];
    #pragma unroll
    for (int i = 0; i < 8; i++) acc[i] = 0.f;
    int choff = g * 32 + q4 * 8;
    #pragma unroll
    for (int si = 0; si < 2; si++) {
        float l0 = s_twl[ql][si * 32 + g * 4 + 0], l1 = s_twl[ql][si * 32 + g * 4 + 1];
        float l2 = s_twl[ql][si * 32 + g * 4 + 2], l3 = s_twl[ql][si * 32 + g * 4 + 3];
        float mx = fmaxf(fmaxf(l0, l1), fmaxf(l2, l3));
        float e0 = __expf(l0 - mx), e1 = __expf(l1 - mx);
        float e2 = __expf(l2 - mx), e3 = __expf(l3 - mx);
        float inv = 1.f / (e0 + e1 + e2 + e3);
        float wts[4] = {e0 * inv, e1 * inv, e2 * inv, e3 * inv};
        int aoff = si * 256;
        float bx = s_base[ql][si * 2], by = s_base[ql][si * 2 + 1];
        #pragma unroll
        for (int pt = 0; pt < 4; pt++) {
            float u = bx + s_toff[ql][g][si * 8 + pt * 2 + 0];
            float v = by + s_toff[ql][g][si * 8 + pt * 2 + 1];
            float ix = u * (float)BW - 0.5f;
            float iy = v * (float)BH - 0.5f;
            float x0f = floorf(ix), y0f = floorf(iy);
            int x0 = (int)x0f, y0 = (int)y0f;
            float wx1 = ix - x0f, wy1 = iy - y0f;
            float wx0 = 1.f - wx1, wy0 = 1.f - wy1;
            #pragma unroll
            for (int cy = 0; cy < 2; cy++) {
                int yy = y0 + cy;
                if ((unsigned)yy >= BH) continue;
                float wy = cy ? wy1 : wy0;
                #pragma unroll
                for (int cx = 0; cx < 2; cx++) {
                    int xx = x0 + cx;
                    if ((unsigned)xx >= BW) continue;
                    float wq = wts[pt] * wy * (cx ? wx1 : wx0);
                    uint4 uu = *reinterpret_cast<const uint4*>(
                        ai + (long)(yy * BW + xx) * 512 + aoff + choff);
                    acc[0] += wq * __uint_as_float(uu.x << 16);
                    acc[1] += wq * __uint_as_float(uu.x & 0xFFFF0000u);
                    acc[2] += wq * __uint_as_float(uu.y << 16);
                    acc[3] += wq * __uint_as_float(uu.y & 0xFFFF0000u);
                    acc[4] += wq * __uint_as_float(uu.z << 16);
                    acc[5] += wq * __uint_as_float(uu.z & 0xFFFF0000u);
                    acc[6] += wq * __uint_as_float(uu.w << 16);
                    acc[7] += wq * __uint_as_float(uu.w & 0xFFFF0000u);
                }
            }
        }
    }
    uint4 o;
    o.x = pack2(acc[0] * 0.5f, acc[1] * 0.5f);
    o.y = pack2(acc[2] * 0.5f, acc[3] * 0.5f);
    o.z = pack2(acc[4] * 0.5f, acc[5] * 0.5f);
    o.w = pack2(acc[6] * 0.5f, acc[7] * 0.5f);
    *reinterpret_cast<uint4*>(tfB + (n0 + ql) * 256 + choff) = o;
}

// ---------------- Spatial cross-attention sampling (8 queries/block, 8 ch/thread) ----------------
__global__ __launch_bounds__(256) void spatial_kernel(const bf16* __restrict__ soffB,
                                                      const bf16* __restrict__ swlB,
                                                      const void* __restrict__ refcam,
                                                      const void* __restrict__ bmask,
                                                      const bf16* __restrict__ imgT,
                                                      const void* __restrict__ img_raw,
                                                      int use_imgT,
                                                      const int* __restrict__ flags,
                                                      bf16* __restrict__ sfB) {
    int tid = threadIdx.x;
    int ql = tid >> 5, t = tid & 31;
    int g = t >> 2, q4 = t & 3;
    long n0 = (long)blockIdx.x * 8;
    __shared__ float s_soff[8][8][33];       // [q][g][p*8+s*2+e] (padded)
    __shared__ float s_swl[8][128];
    __shared__ float s_ref[8][NC][PP][2];
    __shared__ int   s_vis[8][NC][PP];
    __shared__ float s_w[8][NC][8][17];      // normalized weights (padded)
    for (int i = tid; i < 8 * 256; i += 256) {
        int q = i >> 8, j = i & 255;
        s_soff[q][j >> 5][j & 31] = b2f(soffB[n0 * 256 + i]);
    }
    for (int i = tid; i < 8 * 128; i += 256) s_swl[i >> 7][i & 127] = b2f(swlB[n0 * 128 + i]);
    int fdt = flags[0], msz = flags[1];
    for (int i = tid; i < 8 * 48; i += 256) {
        int q = i / 48, r = i % 48;
        s_ref[q][r >> 3][(r & 7) >> 1][r & 1] =
            load_any(refcam, ((long)(r >> 3) * N_Q + n0 + q) * 8 + (r & 7), fdt);
    }
    for (int i = tid; i < 8 * 24; i += 256) {
        int q = i / 24, r = i % 24; int c = r >> 2, p = r & 3;
        long idx = ((long)c * N_Q + n0 + q) * 4 + p;
        int v;
        if (msz == 1)      v = ((const unsigned char*)bmask)[idx] != 0;
        else if (msz == 2) v = ((const unsigned short*)bmask)[idx] != 0;
        else if (msz == 4) v = ((const unsigned int*)bmask)[idx] != 0u;
        else               v = ((const unsigned long long*)bmask)[idx] != 0ULL;
        s_vis[q][c][p] = v;
    }
    __syncthreads();
    // precompute masked-softmax weights per (q, cam, head)
    for (int i = tid; i < 8 * 48; i += 256) {
        int q = i / 48, r = i % 48; int c = r / 8, gg = r & 7;
        float wv[16], mx = -3e38f;
        #pragma unroll
        for (int j = 0; j < 16; j++) {
            float li = s_vis[q][c][j >> 2] ? s_swl[q][gg * 16 + j] : -3e38f;
            wv[j] = li; mx = fmaxf(mx, li);
        }
        float sum = 0.f;
        #pragma unroll
        for (int j = 0; j < 16; j++) {
            float e = (wv[j] > -1e37f) ? __expf(wv[j] - mx) : 0.f;
            wv[j] = e; sum += e;
        }
        float inv = 1.f / fmaxf(sum, 1e-20f);
        #pragma unroll
        for (int j = 0; j < 16; j++) s_w[q][c][gg][j] = wv[j] * inv;
    }
    __syncthreads();
    float acc[8];
    #pragma unroll
    for (int i = 0; i < 8; i++) acc[i] = 0.f;
    float cnt = 0.f;
    int choff = g * 32 + q4 * 8;
    for (int c = 0; c < NC; c++) {
        if (!(s_vis[ql][c][0] | s_vis[ql][c][1] | s_vis[ql][c][2] | s_vis[ql][c][3])) continue;
        cnt += 1.f;
        const bf16* img = imgT + (long)c * HF * WF * 256 + choff;
        #pragma unroll
        for (int p = 0; p < PP; p++) {
            if (!s_vis[ql][c][p]) continue;
            float rx = s_ref[ql][c][p][0], ry = s_ref[ql][c][p][1];
            #pragma unroll
            for (int s = 0; s < PS; s++) {
                float wi = s_w[ql][c][g][p * 4 + s];
                float u = rx + s_soff[ql][g][p * 8 + s * 2 + 0];
                float v = ry + s_soff[ql][g][p * 8 + s * 2 + 1];
                float ix = u * (float)WF - 0.5f, iy = v * (float)HF - 0.5f;
                float x0f = floorf(ix), y0f = floorf(iy);
                int x0 = (int)x0f, y0 = (int)y0f;
                float wx1 = ix - x0f, wy1 = iy - y0f;
                float wx0 = 1.f - wx1, wy0 = 1.f - wy1;
                #pragma unroll
                for (int cy = 0; cy < 2; cy++) {
                    int yy = y0 + cy;
                    if ((unsigned)yy >= HF) continue;
                    float wy = cy ? wy1 : wy0;
                    #pragma unroll
                    for (int cx = 0; cx < 2; cx++) {
                        int xx = x0 + cx;
                        if ((unsigned)xx >= WF) continue;
                        float wq = wi * wy * (cx ? wx1 : wx0);
                        if (use_imgT) {
                            uint4 uu = *reinterpret_cast<const uint4*>(img + (long)(yy * WF + xx) * 256);
                            acc[0] += wq * __uint_as_float(uu.x << 16);
                            acc[1] += wq * __uint_as_float(uu.x & 0xFFFF0000u);
                            acc[2] += wq * __uint_as_float(uu.y << 16);
                            acc[3] += wq * __uint_as_float(uu.y & 0xFFFF0000u);
                            acc[4] += wq * __uint_as_float(uu.z << 16);
                            acc[5] += wq * __uint_as_float(uu.z & 0xFFFF0000u);
                            acc[6] += wq * __uint_as_float(uu.w << 16);
                            acc[7] += wq * __uint_as_float(uu.w & 0xFFFF0000u);
                        } else {
                            #pragma unroll
                            for (int e = 0; e < 8; e++)
                                acc[e] += wq * load_any(img_raw,
                                    (((long)c * 256 + choff + e) * HF + yy) * WF + xx, fdt);
                        }
                    }
                }
            }
        }
    }
    float invc = 1.f / fmaxf(cnt, 1.f);
    uint4 o;
    o.x = pack2(acc[0] * invc, acc[1] * invc);
    o.y = pack2(acc[2] * invc, acc[3] * invc);
    o.z = pack2(acc[4] * invc, acc[5] * invc);
    o.w = pack2(acc[6] * invc, acc[7] * invc);
    *reinterpret_cast<uint4*>(sfB + (n0 + ql) * 256 + choff) = o;
}

// ---------------- Fused FFN: LN3 -> @w1+b1, relu -> @w2+b2, + residual -> out (adaptive dtype) ----
#define FTM 4
__global__ __launch_bounds__(256) void ffn_kernel(const float* __restrict__ x,
                                                  const bf16* __restrict__ g3,
                                                  const bf16* __restrict__ b3,
                                                  const bf16* __restrict__ w1,
                                                  const bf16* __restrict__ b1,
                                                  const bf16* __restrict__ w2,
                                                  const bf16* __restrict__ b2v,
                                                  void* __restrict__ out,
                                                  const int* __restrict__ flags) {
    __shared__ __align__(16) float xlT[D_MODEL][FTM];
    __shared__ __align__(16) float hT[DFF][FTM];
    __shared__ float red[256];
    int tid = threadIdx.x;
    int row0 = blockIdx.x * FTM;
    float gg = b2f(g3[tid]), gb = b2f(b3[tid]);
    #pragma unroll
    for (int r = 0; r < FTM; r++) {
        float v = x[(long)(row0 + r) * D_MODEL + tid];
        red[tid] = v; __syncthreads();
        #pragma unroll
        for (int s = 128; s > 0; s >>= 1) { if (tid < s) red[tid] += red[tid + s]; __syncthreads(); }
        float mu = red[0] * (1.f / 256.f); __syncthreads();
        float d = v - mu;
        red[tid] = d * d; __syncthreads();
        #pragma unroll
        for (int s = 128; s > 0; s >>= 1) { if (tid < s) red[tid] += red[tid + s]; __syncthreads(); }
        float var = red[0] * (1.f / 256.f); __syncthreads();
        xlT[tid][r] = d * rsqrtf(var + 1e-5f) * gg + gb;
    }
    __syncthreads();
    #pragma unroll
    for (int q = 0; q < 4; q++) {
        int jj = tid + q * 256;
        float a0 = 0, a1 = 0, a2 = 0, a3 = 0;
        #pragma unroll 4
        for (int k = 0; k < 256; k++) {
            float wv = b2f(w1[(long)k * DFF + jj]);
            const float4 a = *reinterpret_cast<const float4*>(&xlT[k][0]);
            a0 += a.x * wv; a1 += a.y * wv; a2 += a.z * wv; a3 += a.w * wv;
        }
        float bb = b2f(b1[jj]);
        hT[jj][0] = fmaxf(a0 + bb, 0.f);
        hT[jj][1] = fmaxf(a1 + bb, 0.f);
        hT[jj][2] = fmaxf(a2 + bb, 0.f);
        hT[jj][3] = fmaxf(a3 + bb, 0.f);
    }
    __syncthreads();
    float a0 = 0, a1 = 0, a2 = 0, a3 = 0;
    #pragma unroll 4
    for (int k = 0; k < DFF; k++) {
        float wv = b2f(w2[(long)k * D_MODEL + tid]);
        const float4 a = *reinterpret_cast<const float4*>(&hT[k][0]);
        a0 += a.x * wv; a1 += a.y * wv; a2 += a.z * wv; a3 += a.w * wv;
    }
    float bb = b2f(b2v[tid]);
    int f = flags[0];
    store_any(out, (long)(row0 + 0) * D_MODEL + tid, f, x[(long)(row0 + 0) * D_MODEL + tid] + a0 + bb);
    store_any(out, (long)(row0 + 1) * D_MODEL + tid, f, x[(long)(row0 + 1) * D_MODEL + tid] + a1 + bb);
    store_any(out, (long)(row0 + 2) * D_MODEL + tid, f, x[(long)(row0 + 2) * D_MODEL + tid] + a2 + bb);
    store_any(out, (long)(row0 + 3) * D_MODEL + tid, f, x[(long)(row0 + 3) * D_MODEL + tid] + a3 + bb);
}

// bf16 element offsets inside the weight region
#define W_TOFF_W 0
#define W_TOFF_B 65536
#define W_TWT_W  65664
#define W_TWT_B  98432
#define W_TOUT_W 98496
#define W_TOUT_B 164032
#define W_SOFF_W 164288
#define W_SOFF_B 229824
#define W_SWT_W  230080
#define W_SWT_B  262848
#define W_SOUT_W 262976
#define W_SOUT_B 328512
#define W_FFN_W1 328768
#define W_FFN_B1 590912
#define W_FFN_W2 591936
#define W_FFN_B2 854080
#define W_LN1_G  854336
#define W_LN1_B  854592
#define W_LN2_G  854848
#define W_LN2_B  855104
#define W_LN3_G  855360
#define W_LN3_B  855616

// byte offsets in workspace (total 35,576,320 B)
#define OB_WGT   0
#define OB_FLAGS 1711744
#define OB_AI    1712640
#define OB_TF    11952640
#define OB_X     17072640
#define OB_T4    27312640
#define OB_IMG   31152640
#define WS_NEED_IMG 35576320ULL

extern "C" void kernel_launch(void* const* d_in, const int* in_sizes, int n_in,
                              void* d_out, int out_size, void* d_ws, size_t ws_size,
                              hipStream_t stream) {
    char* W8 = (char*)d_ws;
    bf16*  wgt   = (bf16*)(W8 + OB_WGT);
    int*   flags = (int*)(W8 + OB_FLAGS);
    bf16*  ai    = (bf16*)(W8 + OB_AI);                 // N x 512, pb | q1
    bf16*  q2B   = ai;                                  // N x 256 (after temporal)
    bf16*  sfB   = (bf16*)(W8 + OB_AI + 5120000);       // N x 256
    bf16*  tfB   = (bf16*)(W8 + OB_TF);                 // N x 256
    bf16*  soffB = tfB;                                 // N x 256 (after t_out gemm)
    float* x     = (float*)(W8 + OB_X);                 // N x 256 f32 trunk
    bf16*  toffB = (bf16*)(W8 + OB_T4);                 // N x 128
    bf16*  twlB  = (bf16*)(W8 + OB_T4 + 2560000);       // N x 64
    bf16*  swlB  = toffB;                               // N x 128 (after temporal)
    bf16*  imgT  = (bf16*)(W8 + OB_IMG);                // NC*HF*WF*256
    int use_imgT = (ws_size >= WS_NEED_IMG) ? 1 : 0;

    detect_kernel<<<1, 256, 0, stream>>>(d_in[22] /*ln1_g*/, d_in[28] /*bev_mask*/, flags);

    {
        WCvt wc;
        const int srcs[NW] = {6,7,8,9,10,11,12,13,14,15,16,17,18,19,20,21,22,23,24,25,26,27};
        const int offs[NW] = {W_TOFF_W,W_TOFF_B,W_TWT_W,W_TWT_B,W_TOUT_W,W_TOUT_B,
                              W_SOFF_W,W_SOFF_B,W_SWT_W,W_SWT_B,W_SOUT_W,W_SOUT_B,
                              W_FFN_W1,W_FFN_B1,W_FFN_W2,W_FFN_B2,
                              W_LN1_G,W_LN1_B,W_LN2_G,W_LN2_B,W_LN3_G,W_LN3_B};
        const int cnts[NW] = {65536,128,32768,64,65536,256,65536,256,32768,128,65536,256,
                              262144,1024,262144,256,256,256,256,256,256,256};
        int blk = 0;
        for (int a = 0; a < NW; a++) {
            wc.src[a] = d_in[srcs[a]];
            wc.dst_off[a] = offs[a];
            wc.count[a] = cnts[a];
            wc.blk_start[a] = blk;
            blk += (cnts[a] + 255) / 256;
        }
        wc.blk_start[NW] = blk;
        cvt_w_kernel<<<blk, 256, 0, stream>>>(wc, wgt, flags);
    }

    ln_kernel<<<N_Q, 256, 0, stream>>>(d_in[1], 1, flags, wgt + W_LN1_G, wgt + W_LN1_B, ai, 512, 0);
    ln_kernel<<<N_Q, 256, 0, stream>>>(d_in[0], 1, flags, wgt + W_LN1_G, wgt + W_LN1_B, ai, 512, 256);
    gemm_kernel<512, 128, 16><<<625, 128, 0, stream>>>(ai, 512, wgt + W_TOFF_W, wgt + W_TOFF_B,
        1, T_RAD, toffB, nullptr, 128, nullptr, nullptr, flags);
    gemm_kernel<512, 64, 16><<<625, 64, 0, stream>>>(ai, 512, wgt + W_TWT_W, wgt + W_TWT_B,
        0, 0.f, twlB, nullptr, 64, nullptr, nullptr, flags);
    temporal_kernel<<<1250, 256, 0, stream>>>(ai, toffB, twlB, d_in[3], d_in[5], flags, tfB);
    gemm_kernel<256, 256, 16><<<625, 256, 0, stream>>>(tfB, 256, wgt + W_TOUT_W, wgt + W_TOUT_B,
        2, 0.f, nullptr, x, 256, d_in[0], nullptr, flags);
    ln_kernel<<<N_Q, 256, 0, stream>>>(x, 0, flags, wgt + W_LN2_G, wgt + W_LN2_B, q2B, 256, 0);
    gemm_kernel<256, 256, 16><<<625, 256, 0, stream>>>(q2B, 256, wgt + W_SOFF_W, wgt + W_SOFF_B,
        1, S_RAD, soffB, nullptr, 256, nullptr, nullptr, flags);
    gemm_kernel<256, 128, 16><<<625, 128, 0, stream>>>(q2B, 256, wgt + W_SWT_W, wgt + W_SWT_B,
        0, 0.f, swlB, nullptr, 128, nullptr, nullptr, flags);
    if (use_imgT)
        transpose_img<<<8640, 256, 0, stream>>>(d_in[2], imgT, flags);
    spatial_kernel<<<1250, 256, 0, stream>>>(soffB, swlB, d_in[4], d_in[28], imgT, d_in[2],
                                             use_imgT, flags, sfB);
    gemm_kernel<256, 256, 16><<<625, 256, 0, stream>>>(sfB, 256, wgt + W_SOUT_W, wgt + W_SOUT_B,
        3, 0.f, nullptr, x, 256, nullptr, x, flags);
    ffn_kernel<<<2500, 256, 0, stream>>>(x, wgt + W_LN3_G, wgt + W_LN3_B,
                                         wgt + W_FFN_W1, wgt + W_FFN_B1,
                                         wgt + W_FFN_W2, wgt + W_FFN_B2, d_out, flags);
}

// Round 5
// 650.588 us; speedup vs baseline: 1.9650x; 1.4601x over previous
//
#include <hip/hip_runtime.h>
#include <hip/hip_bf16.h>
#include <hip/hip_fp16.h>

#define N_Q 10000
#define D_MODEL 256
#define NH 8
#define PT 4
#define PP 4
#define PS 4
#define DFF 1024
#define NC 6
#define HF 24
#define WF 60
#define BH 100
#define BW 100
#define T_RAD 0.15f
#define S_RAD 0.12f

typedef __hip_bfloat16 bf16;
typedef __attribute__((ext_vector_type(8))) short short8;
typedef __attribute__((ext_vector_type(4))) float f32x4;

__device__ __forceinline__ float b2f(bf16 v) { return __bfloat162float(v); }
__device__ __forceinline__ bf16 f2b(float v) { return __float2bfloat16(v); }

__device__ __forceinline__ f32x4 mfma16(short8 a, short8 b, f32x4 c) {
    return __builtin_amdgcn_mfma_f32_16x16x32_bf16(a, b, c, 0, 0, 0);
}

// dtype-adaptive loads/stores; f: 0=f32, 1=bf16, 2=f16
__device__ __forceinline__ float load_any(const void* p, long i, int f) {
    if (f == 0) return ((const float*)p)[i];
    if (f == 1) return b2f(((const bf16*)p)[i]);
    return __half2float(((const __half*)p)[i]);
}
__device__ __forceinline__ void store_any(void* p, long i, int f, float v) {
    if (f == 0)      ((float*)p)[i] = v;
    else if (f == 1) ((bf16*)p)[i] = f2b(v);
    else             ((__half*)p)[i] = __float2half(v);
}

__device__ __forceinline__ unsigned pack2(float a, float b) {
    bf16 x = f2b(a), y = f2b(b);
    unsigned short ux = *(unsigned short*)&x, uy = *(unsigned short*)&y;
    return (unsigned)ux | ((unsigned)uy << 16);
}

// ---------------- dtype / mask-width detection (parallel) ----------------
__global__ __launch_bounds__(256) void detect_kernel(const void* __restrict__ ln1g,
                                                     const void* __restrict__ mask,
                                                     int* __restrict__ flags) {
    __shared__ int sh[6];
    int tid = threadIdx.x;
    if (tid < 6) sh[tid] = (tid == 0 || tid == 2 || tid == 4) ? 1 : 0;
    __syncthreads();
    const unsigned long long* m64 = (const unsigned long long*)mask;
    const unsigned int*       m32 = (const unsigned int*)mask;
    const unsigned short*     m16 = (const unsigned short*)mask;
    int lok8 = 1, lones8 = 0, lok4 = 1, lones4 = 0, lok2 = 1, lones2 = 0;
    for (int i = tid; i < 480; i += 256) {
        if (i < 120) {
            unsigned long long v = m64[i];
            if (v == 1ULL) lones8++; else if (v != 0ULL) lok8 = 0;
        }
        if (i < 240) {
            unsigned int v = m32[i];
            if (v == 1u || v == 0x3F800000u) lones4++; else if (v != 0u) lok4 = 0;
        }
        unsigned short v = m16[i];
        if (v == 1 || v == 0x3F80) lones2++; else if (v != 0) lok2 = 0;
    }
    atomicAnd(&sh[0], lok8); atomicAdd(&sh[1], lones8);
    atomicAnd(&sh[2], lok4); atomicAdd(&sh[3], lones4);
    atomicAnd(&sh[4], lok2); atomicAdd(&sh[5], lones2);
    __syncthreads();
    if (tid == 0) {
        unsigned short u0 = ((const unsigned short*)ln1g)[0];
        flags[0] = (u0 == 0x3F80) ? 1 : (u0 == 0x3C00 ? 2 : 0);
        int ms;
        if (sh[0] && sh[1] > 30)       ms = 8;
        else if (sh[2] && sh[3] > 60)  ms = 4;
        else if (sh[4] && sh[5] > 120) ms = 2;
        else                           ms = 1;
        flags[1] = ms;
    }
}

// ---------------- weight matrix transpose: src [R][C] -> dst [C][R] bf16 ----------------
__global__ __launch_bounds__(256) void transpose_w(const void* __restrict__ src,
                                                   bf16* __restrict__ dst, int R, int C,
                                                   const int* __restrict__ flags) {
    int i = blockIdx.x * 256 + threadIdx.x;
    if (i >= R * C) return;
    int c = i / R, r = i % R;
    dst[i] = f2b(load_any(src, (long)r * C + c, flags[0]));
}

// ---------------- batched bias/LN-param conversion -> bf16 ----------------
#define NW 14
struct WCvt {
    const void* src[NW];
    int dst_off[NW];
    int count[NW];
    int blk_start[NW + 1];
};
__global__ __launch_bounds__(256) void cvt_w_kernel(WCvt wc, bf16* __restrict__ dst,
                                                    const int* __restrict__ flags) {
    int blk = blockIdx.x;
    int a = 0;
    while (a < NW - 1 && blk >= wc.blk_start[a + 1]) a++;
    int i = (blk - wc.blk_start[a]) * 256 + threadIdx.x;
    if (i >= wc.count[a]) return;
    dst[wc.dst_off[a] + i] = f2b(load_any(wc.src[a], i, flags[0]));
}

// ---------------- image_feats (c, ch, y, x) -> imgT (c, y, x, ch) bf16 ----------------
__global__ __launch_bounds__(256) void transpose_img(const void* __restrict__ in,
                                                     bf16* __restrict__ out,
                                                     const int* __restrict__ flags) {
    int i = blockIdx.x * 256 + threadIdx.x;
    if (i >= NC * HF * WF * 256) return;
    int ch = i & 255;
    int t = i >> 8;
    int xx = t % WF; t /= WF;
    int yy = t % HF;
    int c  = t / HF;
    long src = (((long)(c * 256) + ch) * HF + yy) * WF + xx;
    out[i] = f2b(load_any(in, src, flags[0]));
}

// ---------------- LayerNorm over D=256, one row per block -> bf16 out ----------------
__global__ __launch_bounds__(256) void ln_kernel(const void* __restrict__ in, int kind,
                                                 const int* __restrict__ flags,
                                                 const bf16* __restrict__ g,
                                                 const bf16* __restrict__ b,
                                                 bf16* __restrict__ out, int ostride, int ooff) {
    int n = blockIdx.x, tid = threadIdx.x;
    float v = kind ? load_any(in, (long)n * D_MODEL + tid, flags[0])
                   : ((const float*)in)[(long)n * D_MODEL + tid];
    __shared__ float red[D_MODEL];
    red[tid] = v; __syncthreads();
    #pragma unroll
    for (int s = 128; s > 0; s >>= 1) { if (tid < s) red[tid] += red[tid + s]; __syncthreads(); }
    float mu = red[0] * (1.f / D_MODEL); __syncthreads();
    float d = v - mu;
    red[tid] = d * d; __syncthreads();
    #pragma unroll
    for (int s = 128; s > 0; s >>= 1) { if (tid < s) red[tid] += red[tid + s]; __syncthreads(); }
    float var = red[0] * (1.f / D_MODEL);
    out[(long)n * ostride + ooff + tid] = f2b(d * rsqrtf(var + 1e-5f) * b2f(g[tid]) + b2f(b[tid]));
}

// ---------------- MFMA GEMM: out[M,J] = A[M,K](bf16) @ WT[J,K]^T + bias ----------------
// M-tile 32, 4 waves as (row-half, col-half). Modes: 0 ->bf16; 1 tanh*scale ->bf16;
// 2 + raw residual ->f32; 3 + f32 residual ->f32.   ldo == J.
template <int K, int J, int MODE>
__global__ __launch_bounds__(256) void gemm_mfma(const bf16* __restrict__ A,
                                                 const bf16* __restrict__ WT,
                                                 const bf16* __restrict__ bias,
                                                 float scale,
                                                 bf16* __restrict__ outb, float* __restrict__ outf,
                                                 const void* __restrict__ resraw,
                                                 const float* __restrict__ resf,
                                                 const int* __restrict__ flags) {
    constexpr int MT = 32;
    constexpr int LDK = K + 8;   // stride ≡ 8 mod 64 elems -> 2-way (free) LDS aliasing
    __shared__ bf16 As[MT * LDK];
    int tid = threadIdx.x;
    int row0 = blockIdx.x * MT;
    for (int t = tid; t < MT * (K / 8); t += 256) {
        int r = t / (K / 8), kq = t % (K / 8);
        uint4 u = {0u, 0u, 0u, 0u};
        if (row0 + r < N_Q)
            u = *reinterpret_cast<const uint4*>(A + (size_t)(row0 + r) * K + kq * 8);
        *reinterpret_cast<uint4*>(&As[r * LDK + kq * 8]) = u;
    }
    __syncthreads();
    int wave = tid >> 6, lane = tid & 63;
    int l = lane & 15, quad = lane >> 4;
    int rh = wave >> 1, chalf = wave & 1;
    constexpr int NK = K / 32;
    constexpr int NCT = J / 32;
    short8 afr[NK];
    const bf16* arow = &As[(rh * 16 + l) * LDK + quad * 8];
    #pragma unroll
    for (int ks = 0; ks < NK; ks++)
        afr[ks] = *reinterpret_cast<const short8*>(arow + ks * 32);
    int fdt = flags[0];
    for (int ct = 0; ct < NCT; ct++) {
        int col = chalf * (J / 2) + ct * 16 + l;
        const bf16* wrow = WT + (size_t)col * K + quad * 8;
        f32x4 acc = {0.f, 0.f, 0.f, 0.f};
        #pragma unroll
        for (int ks = 0; ks < NK; ks++) {
            short8 bfr = *reinterpret_cast<const short8*>(wrow + ks * 32);
            acc = mfma16(afr[ks], bfr, acc);
        }
        float bb = b2f(bias[col]);
        #pragma unroll
        for (int r = 0; r < 4; r++) {
            int row = row0 + rh * 16 + quad * 4 + r;
            if (row >= N_Q) continue;
            long o = (long)row * J + col;
            float v = acc[r] + bb;
            if (MODE == 0)      outb[o] = f2b(v);
            else if (MODE == 1) outb[o] = f2b(tanhf(v) * scale);
            else if (MODE == 2) outf[o] = v + load_any(resraw, o, fdt);
            else                outf[o] = v + resf[o];
        }
    }
}

// ---------------- Fused MFMA FFN: LN3 -> @w1T,relu -> @w2T -> +x -> out ----------------
// M-tile 16 (grid 625, exact). h[16][1032] bf16 in LDS (33 KB), xl overlaid at base.
__global__ __launch_bounds__(256) void ffn_mfma(const float* __restrict__ x,
                                                const bf16* __restrict__ g3,
                                                const bf16* __restrict__ b3,
                                                const bf16* __restrict__ w1T,  // [1024][256]
                                                const bf16* __restrict__ b1,
                                                const bf16* __restrict__ w2T,  // [256][1024]
                                                const bf16* __restrict__ b2v,
                                                void* __restrict__ out,
                                                const int* __restrict__ flags) {
    constexpr int LDH = DFF + 8;      // 1032: stride 2064 B, 16-B aligned, 2-way LDS aliasing
    constexpr int LDX = D_MODEL + 8;  // 264
    __shared__ bf16 hbuf[16 * LDH];
    bf16* xl = hbuf;                  // [16][264] overlay; consumed before h writes
    int tid = threadIdx.x;
    int row0 = blockIdx.x * 16;
    {
        int r = tid >> 4, lr = tid & 15;
        const float* xr = x + (long)(row0 + r) * 256 + lr * 16;
        float vals[16];
        float s1 = 0.f, s2 = 0.f;
        #pragma unroll
        for (int i = 0; i < 16; i++) {
            float v = xr[i];
            vals[i] = v; s1 += v; s2 += v * v;
        }
        #pragma unroll
        for (int off = 8; off > 0; off >>= 1) {
            s1 += __shfl_down(s1, off, 16);
            s2 += __shfl_down(s2, off, 16);
        }
        s1 = __shfl(s1, 0, 16);
        s2 = __shfl(s2, 0, 16);
        float mu = s1 * (1.f / 256.f);
        float var = s2 * (1.f / 256.f) - mu * mu;
        float inv = rsqrtf(var + 1e-5f);
        #pragma unroll
        for (int i = 0; i < 16; i++) {
            int k = lr * 16 + i;
            xl[r * LDX + k] = f2b((vals[i] - mu) * inv * b2f(g3[k]) + b2f(b3[k]));
        }
    }
    __syncthreads();
    int wave = tid >> 6, lane = tid & 63;
    int l = lane & 15, quad = lane >> 4;
    short8 afr[8];
    {
        const bf16* arow = xl + l * LDX + quad * 8;
        #pragma unroll
        for (int ks = 0; ks < 8; ks++)
            afr[ks] = *reinterpret_cast<const short8*>(arow + ks * 32);
    }
    __syncthreads();  // all a-frags in regs before h overwrites xl
    // layer 1: wave handles 256 cols (16 col-tiles), K=256
    for (int ct = 0; ct < 16; ct++) {
        int col = wave * 256 + ct * 16 + l;
        const bf16* wrow = w1T + (size_t)col * 256 + quad * 8;
        f32x4 acc = {0.f, 0.f, 0.f, 0.f};
        #pragma unroll
        for (int ks = 0; ks < 8; ks++) {
            short8 bfr = *reinterpret_cast<const short8*>(wrow + ks * 32);
            acc = mfma16(afr[ks], bfr, acc);
        }
        float bb = b2f(b1[col]);
        #pragma unroll
        for (int r = 0; r < 4; r++)
            hbuf[(quad * 4 + r) * LDH + col] = f2b(fmaxf(acc[r] + bb, 0.f));
    }
    __syncthreads();
    // layer 2: wave handles 64 cols (4 col-tiles), K=1024
    int fdt = flags[0];
    for (int ct = 0; ct < 4; ct++) {
        int col = wave * 64 + ct * 16 + l;
        const bf16* wrow = w2T + (size_t)col * 1024 + quad * 8;
        const bf16* hrow = hbuf + l * LDH + quad * 8;
        f32x4 acc = {0.f, 0.f, 0.f, 0.f};
        #pragma unroll 8
        for (int ks = 0; ks < 32; ks++) {
            short8 a2 = *reinterpret_cast<const short8*>(hrow + ks * 32);
            short8 bfr = *reinterpret_cast<const short8*>(wrow + ks * 32);
            acc = mfma16(a2, bfr, acc);
        }
        float bb = b2f(b2v[col]);
        #pragma unroll
        for (int r = 0; r < 4; r++) {
            long o = (long)(row0 + quad * 4 + r) * 256 + col;
            store_any(out, o, fdt, x[o] + acc[r] + bb);
        }
    }
}

// ---------------- Temporal deformable sampling (8 queries/block, 8 ch/thread) ----------------
__global__ __launch_bounds__(256) void temporal_kernel(const bf16* __restrict__ ai,
                                                       const bf16* __restrict__ toffB,
                                                       const bf16* __restrict__ twlB,
                                                       const void* __restrict__ ref2d,
                                                       const void* __restrict__ ego,
                                                       const int* __restrict__ flags,
                                                       bf16* __restrict__ tfB) {
    int tid = threadIdx.x;
    int ql = tid >> 5, t = tid & 31;
    int g = t >> 2, q4 = t & 3;
    long n0 = (long)blockIdx.x * 8;
    __shared__ float s_toff[8][8][17];
    __shared__ float s_twl[8][64];
    __shared__ float s_base[8][4];
    for (int i = tid; i < 8 * 128; i += 256) {
        int q = i >> 7, j = i & 127;
        int si = j >> 6, r = j & 63, gg = r >> 3, w = r & 7;
        s_toff[q][gg][si * 8 + w] = b2f(toffB[n0 * 128 + i]);
    }
    for (int i = tid; i < 8 * 64; i += 256) s_twl[i >> 6][i & 63] = b2f(twlB[n0 * 64 + i]);
    if (tid < 8) {
        int f = flags[0];
        float rx = load_any(ref2d, (n0 + tid) * 2, f), ry = load_any(ref2d, (n0 + tid) * 2 + 1, f);
        s_base[tid][0] = rx + load_any(ego, 0, f); s_base[tid][1] = ry + load_any(ego, 1, f);
        s_base[tid][2] = rx;                       s_base[tid][3] = ry;
    }
    __syncthreads();
    float acc[8];
    #pragma unroll
    for (int i = 0; i < 8; i++) acc[i] = 0.f;
    int choff = g * 32 + q4 * 8;
    #pragma unroll
    for (int si = 0; si < 2; si++) {
        float l0 = s_twl[ql][si * 32 + g * 4 + 0], l1 = s_twl[ql][si * 32 + g * 4 + 1];
        float l2 = s_twl[ql][si * 32 + g * 4 + 2], l3 = s_twl[ql][si * 32 + g * 4 + 3];
        float mx = fmaxf(fmaxf(l0, l1), fmaxf(l2, l3));
        float e0 = __expf(l0 - mx), e1 = __expf(l1 - mx);
        float e2 = __expf(l2 - mx), e3 = __expf(l3 - mx);
        float inv = 1.f / (e0 + e1 + e2 + e3);
        float wts[4] = {e0 * inv, e1 * inv, e2 * inv, e3 * inv};
        int aoff = si * 256;
        float bx = s_base[ql][si * 2], by = s_base[ql][si * 2 + 1];
        #pragma unroll
        for (int pt = 0; pt < 4; pt++) {
            float u = bx + s_toff[ql][g][si * 8 + pt * 2 + 0];
            float v = by + s_toff[ql][g][si * 8 + pt * 2 + 1];
            float ix = u * (float)BW - 0.5f;
            float iy = v * (float)BH - 0.5f;
            float x0f = floorf(ix), y0f = floorf(iy);
            int x0 = (int)x0f, y0 = (int)y0f;
            float wx1 = ix - x0f, wy1 = iy - y0f;
            float wx0 = 1.f - wx1, wy0 = 1.f - wy1;
            #pragma unroll
            for (int cy = 0; cy < 2; cy++) {
                int yy = y0 + cy;
                if ((unsigned)yy >= BH) continue;
                float wy = cy ? wy1 : wy0;
                #pragma unroll
                for (int cx = 0; cx < 2; cx++) {
                    int xx = x0 + cx;
                    if ((unsigned)xx >= BW) continue;
                    float wq = wts[pt] * wy * (cx ? wx1 : wx0);
                    uint4 uu = *reinterpret_cast<const uint4*>(
                        ai + (long)(yy * BW + xx) * 512 + aoff + choff);
                    acc[0] += wq * __uint_as_float(uu.x << 16);
                    acc[1] += wq * __uint_as_float(uu.x & 0xFFFF0000u);
                    acc[2] += wq * __uint_as_float(uu.y << 16);
                    acc[3] += wq * __uint_as_float(uu.y & 0xFFFF0000u);
                    acc[4] += wq * __uint_as_float(uu.z << 16);
                    acc[5] += wq * __uint_as_float(uu.z & 0xFFFF0000u);
                    acc[6] += wq * __uint_as_float(uu.w << 16);
                    acc[7] += wq * __uint_as_float(uu.w & 0xFFFF0000u);
                }
            }
        }
    }
    uint4 o;
    o.x = pack2(acc[0] * 0.5f, acc[1] * 0.5f);
    o.y = pack2(acc[2] * 0.5f, acc[3] * 0.5f);
    o.z = pack2(acc[4] * 0.5f, acc[5] * 0.5f);
    o.w = pack2(acc[6] * 0.5f, acc[7] * 0.5f);
    *reinterpret_cast<uint4*>(tfB + (n0 + ql) * 256 + choff) = o;
}

// ---------------- Spatial cross-attention sampling (8 queries/block, 8 ch/thread) ----------------
__global__ __launch_bounds__(256) void spatial_kernel(const bf16* __restrict__ soffB,
                                                      const bf16* __restrict__ swlB,
                                                      const void* __restrict__ refcam,
                                                      const void* __restrict__ bmask,
                                                      const bf16* __restrict__ imgT,
                                                      const void* __restrict__ img_raw,
                                                      int use_imgT,
                                                      const int* __restrict__ flags,
                                                      bf16* __restrict__ sfB) {
    int tid = threadIdx.x;
    int ql = tid >> 5, t = tid & 31;
    int g = t >> 2, q4 = t & 3;
    long n0 = (long)blockIdx.x * 8;
    __shared__ float s_soff[8][8][33];
    __shared__ float s_swl[8][128];
    __shared__ float s_ref[8][NC][PP][2];
    __shared__ int   s_vis[8][NC][PP];
    __shared__ float s_w[8][NC][8][17];
    for (int i = tid; i < 8 * 256; i += 256) {
        int q = i >> 8, j = i & 255;
        s_soff[q][j >> 5][j & 31] = b2f(soffB[n0 * 256 + i]);
    }
    for (int i = tid; i < 8 * 128; i += 256) s_swl[i >> 7][i & 127] = b2f(swlB[n0 * 128 + i]);
    int fdt = flags[0], msz = flags[1];
    for (int i = tid; i < 8 * 48; i += 256) {
        int q = i / 48, r = i % 48;
        s_ref[q][r >> 3][(r & 7) >> 1][r & 1] =
            load_any(refcam, ((long)(r >> 3) * N_Q + n0 + q) * 8 + (r & 7), fdt);
    }
    for (int i = tid; i < 8 * 24; i += 256) {
        int q = i / 24, r = i % 24; int c = r >> 2, p = r & 3;
        long idx = ((long)c * N_Q + n0 + q) * 4 + p;
        int v;
        if (msz == 1)      v = ((const unsigned char*)bmask)[idx] != 0;
        else if (msz == 2) v = ((const unsigned short*)bmask)[idx] != 0;
        else if (msz == 4) v = ((const unsigned int*)bmask)[idx] != 0u;
        else               v = ((const unsigned long long*)bmask)[idx] != 0ULL;
        s_vis[q][c][p] = v;
    }
    __syncthreads();
    for (int i = tid; i < 8 * 48; i += 256) {
        int q = i / 48, r = i % 48; int c = r / 8, gg = r & 7;
        float wv[16], mx = -3e38f;
        #pragma unroll
        for (int j = 0; j < 16; j++) {
            float li = s_vis[q][c][j >> 2] ? s_swl[q][gg * 16 + j] : -3e38f;
            wv[j] = li; mx = fmaxf(mx, li);
        }
        float sum = 0.f;
        #pragma unroll
        for (int j = 0; j < 16; j++) {
            float e = (wv[j] > -1e37f) ? __expf(wv[j] - mx) : 0.f;
            wv[j] = e; sum += e;
        }
        float inv = 1.f / fmaxf(sum, 1e-20f);
        #pragma unroll
        for (int j = 0; j < 16; j++) s_w[q][c][gg][j] = wv[j] * inv;
    }
    __syncthreads();
    float acc[8];
    #pragma unroll
    for (int i = 0; i < 8; i++) acc[i] = 0.f;
    float cnt = 0.f;
    int choff = g * 32 + q4 * 8;
    for (int c = 0; c < NC; c++) {
        if (!(s_vis[ql][c][0] | s_vis[ql][c][1] | s_vis[ql][c][2] | s_vis[ql][c][3])) continue;
        cnt += 1.f;
        const bf16* img = imgT + (long)c * HF * WF * 256 + choff;
        #pragma unroll
        for (int p = 0; p < PP; p++) {
            if (!s_vis[ql][c][p]) continue;
            float rx = s_ref[ql][c][p][0], ry = s_ref[ql][c][p][1];
            #pragma unroll
            for (int s = 0; s < PS; s++) {
                float wi = s_w[ql][c][g][p * 4 + s];
                float u = rx + s_soff[ql][g][p * 8 + s * 2 + 0];
                float v = ry + s_soff[ql][g][p * 8 + s * 2 + 1];
                float ix = u * (float)WF - 0.5f, iy = v * (float)HF - 0.5f;
                float x0f = floorf(ix), y0f = floorf(iy);
                int x0 = (int)x0f, y0 = (int)y0f;
                float wx1 = ix - x0f, wy1 = iy - y0f;
                float wx0 = 1.f - wx1, wy0 = 1.f - wy1;
                #pragma unroll
                for (int cy = 0; cy < 2; cy++) {
                    int yy = y0 + cy;
                    if ((unsigned)yy >= HF) continue;
                    float wy = cy ? wy1 : wy0;
                    #pragma unroll
                    for (int cx = 0; cx < 2; cx++) {
                        int xx = x0 + cx;
                        if ((unsigned)xx >= WF) continue;
                        float wq = wi * wy * (cx ? wx1 : wx0);
                        if (use_imgT) {
                            uint4 uu = *reinterpret_cast<const uint4*>(img + (long)(yy * WF + xx) * 256);
                            acc[0] += wq * __uint_as_float(uu.x << 16);
                            acc[1] += wq * __uint_as_float(uu.x & 0xFFFF0000u);
                            acc[2] += wq * __uint_as_float(uu.y << 16);
                            acc[3] += wq * __uint_as_float(uu.y & 0xFFFF0000u);
                            acc[4] += wq * __uint_as_float(uu.z << 16);
                            acc[5] += wq * __uint_as_float(uu.z & 0xFFFF0000u);
                            acc[6] += wq * __uint_as_float(uu.w << 16);
                            acc[7] += wq * __uint_as_float(uu.w & 0xFFFF0000u);
                        } else {
                            #pragma unroll
                            for (int e = 0; e < 8; e++)
                                acc[e] += wq * load_any(img_raw,
                                    (((long)c * 256 + choff + e) * HF + yy) * WF + xx, fdt);
                        }
                    }
                }
            }
        }
    }
    float invc = 1.f / fmaxf(cnt, 1.f);
    uint4 o;
    o.x = pack2(acc[0] * invc, acc[1] * invc);
    o.y = pack2(acc[2] * invc, acc[3] * invc);
    o.z = pack2(acc[4] * invc, acc[5] * invc);
    o.w = pack2(acc[6] * invc, acc[7] * invc);
    *reinterpret_cast<uint4*>(sfB + (n0 + ql) * 256 + choff) = o;
}

// bf16 element offsets inside the weight region (matrices stored TRANSPOSED [J][K])
#define W_TOFF_W 0
#define W_TOFF_B 65536
#define W_TWT_W  65664
#define W_TWT_B  98432
#define W_TOUT_W 98496
#define W_TOUT_B 164032
#define W_SOFF_W 164288
#define W_SOFF_B 229824
#define W_SWT_W  230080
#define W_SWT_B  262848
#define W_SOUT_W 262976
#define W_SOUT_B 328512
#define W_FFN_W1 328768
#define W_FFN_B1 590912
#define W_FFN_W2 591936
#define W_FFN_B2 854080
#define W_LN1_G  854336
#define W_LN1_B  854592
#define W_LN2_G  854848
#define W_LN2_B  855104
#define W_LN3_G  855360
#define W_LN3_B  855616

// byte offsets in workspace (total ~35.6 MB)
#define OB_WGT   0
#define OB_FLAGS 1711744
#define OB_AI    1712640
#define OB_TF    11952640
#define OB_X     17072640
#define OB_T4    27312640
#define OB_IMG   31152640
#define WS_NEED_IMG 35576320ULL

extern "C" void kernel_launch(void* const* d_in, const int* in_sizes, int n_in,
                              void* d_out, int out_size, void* d_ws, size_t ws_size,
                              hipStream_t stream) {
    char* W8 = (char*)d_ws;
    bf16*  wgt   = (bf16*)(W8 + OB_WGT);
    int*   flags = (int*)(W8 + OB_FLAGS);
    bf16*  ai    = (bf16*)(W8 + OB_AI);                 // N x 512, pb | q1
    bf16*  q2B   = ai;                                  // N x 256 (after temporal)
    bf16*  sfB   = (bf16*)(W8 + OB_AI + 5120000);       // N x 256
    bf16*  tfB   = (bf16*)(W8 + OB_TF);                 // N x 256
    bf16*  soffB = tfB;                                 // N x 256 (after t_out gemm)
    float* x     = (float*)(W8 + OB_X);                 // N x 256 f32 trunk
    bf16*  toffB = (bf16*)(W8 + OB_T4);                 // N x 128
    bf16*  twlB  = (bf16*)(W8 + OB_T4 + 2560000);       // N x 64
    bf16*  swlB  = toffB;                               // N x 128 (after temporal)
    bf16*  imgT  = (bf16*)(W8 + OB_IMG);                // NC*HF*WF*256
    int use_imgT = (ws_size >= WS_NEED_IMG) ? 1 : 0;

    detect_kernel<<<1, 256, 0, stream>>>(d_in[22], d_in[28], flags);

    // weight matrices -> bf16, transposed to [J][K]
    transpose_w<<<256, 256, 0, stream>>>(d_in[6],  wgt + W_TOFF_W, 512, 128, flags);
    transpose_w<<<128, 256, 0, stream>>>(d_in[8],  wgt + W_TWT_W,  512, 64,  flags);
    transpose_w<<<256, 256, 0, stream>>>(d_in[10], wgt + W_TOUT_W, 256, 256, flags);
    transpose_w<<<256, 256, 0, stream>>>(d_in[12], wgt + W_SOFF_W, 256, 256, flags);
    transpose_w<<<128, 256, 0, stream>>>(d_in[14], wgt + W_SWT_W,  256, 128, flags);
    transpose_w<<<256, 256, 0, stream>>>(d_in[16], wgt + W_SOUT_W, 256, 256, flags);
    transpose_w<<<1024, 256, 0, stream>>>(d_in[18], wgt + W_FFN_W1, 256, 1024, flags);
    transpose_w<<<1024, 256, 0, stream>>>(d_in[20], wgt + W_FFN_W2, 1024, 256, flags);

    {   // biases + LN params -> bf16 flat
        WCvt wc;
        const int srcs[NW] = {7,9,11,13,15,17,19,21,22,23,24,25,26,27};
        const int offs[NW] = {W_TOFF_B,W_TWT_B,W_TOUT_B,W_SOFF_B,W_SWT_B,W_SOUT_B,
                              W_FFN_B1,W_FFN_B2,W_LN1_G,W_LN1_B,W_LN2_G,W_LN2_B,W_LN3_G,W_LN3_B};
        const int cnts[NW] = {128,64,256,256,128,256,1024,256,256,256,256,256,256,256};
        int blk = 0;
        for (int a = 0; a < NW; a++) {
            wc.src[a] = d_in[srcs[a]];
            wc.dst_off[a] = offs[a];
            wc.count[a] = cnts[a];
            wc.blk_start[a] = blk;
            blk += (cnts[a] + 255) / 256;
        }
        wc.blk_start[NW] = blk;
        cvt_w_kernel<<<blk, 256, 0, stream>>>(wc, wgt, flags);
    }

    ln_kernel<<<N_Q, 256, 0, stream>>>(d_in[1], 1, flags, wgt + W_LN1_G, wgt + W_LN1_B, ai, 512, 0);
    ln_kernel<<<N_Q, 256, 0, stream>>>(d_in[0], 1, flags, wgt + W_LN1_G, wgt + W_LN1_B, ai, 512, 256);
    gemm_mfma<512, 128, 1><<<313, 256, 0, stream>>>(ai, wgt + W_TOFF_W, wgt + W_TOFF_B,
        T_RAD, toffB, nullptr, nullptr, nullptr, flags);
    gemm_mfma<512, 64, 0><<<313, 256, 0, stream>>>(ai, wgt + W_TWT_W, wgt + W_TWT_B,
        0.f, twlB, nullptr, nullptr, nullptr, flags);
    temporal_kernel<<<1250, 256, 0, stream>>>(ai, toffB, twlB, d_in[3], d_in[5], flags, tfB);
    gemm_mfma<256, 256, 2><<<313, 256, 0, stream>>>(tfB, wgt + W_TOUT_W, wgt + W_TOUT_B,
        0.f, nullptr, x, d_in[0], nullptr, flags);
    ln_kernel<<<N_Q, 256, 0, stream>>>(x, 0, flags, wgt + W_LN2_G, wgt + W_LN2_B, q2B, 256, 0);
    gemm_mfma<256, 256, 1><<<313, 256, 0, stream>>>(q2B, wgt + W_SOFF_W, wgt + W_SOFF_B,
        S_RAD, soffB, nullptr, nullptr, nullptr, flags);
    gemm_mfma<256, 128, 0><<<313, 256, 0, stream>>>(q2B, wgt + W_SWT_W, wgt + W_SWT_B,
        0.f, swlB, nullptr, nullptr, nullptr, flags);
    if (use_imgT)
        transpose_img<<<8640, 256, 0, stream>>>(d_in[2], imgT, flags);
    spatial_kernel<<<1250, 256, 0, stream>>>(soffB, swlB, d_in[4], d_in[28], imgT, d_in[2],
                                             use_imgT, flags, sfB);
    gemm_mfma<256, 256, 3><<<313, 256, 0, stream>>>(sfB, wgt + W_SOUT_W, wgt + W_SOUT_B,
        0.f, nullptr, x, nullptr, x, flags);
    ffn_mfma<<<625, 256, 0, stream>>>(x, wgt + W_LN3_G, wgt + W_LN3_B,
                                      wgt + W_FFN_W1, wgt + W_FFN_B1,
                                      wgt + W_FFN_W2, wgt + W_FFN_B2, d_out, flags);
}

// Round 6
// 571.329 us; speedup vs baseline: 2.2376x; 1.1387x over previous
//
#include <hip/hip_runtime.h>
#include <hip/hip_bf16.h>
#include <hip/hip_fp16.h>

#define N_Q 10000
#define D_MODEL 256
#define NH 8
#define PT 4
#define PP 4
#define PS 4
#define DFF 1024
#define NC 6
#define HF 24
#define WF 60
#define BH 100
#define BW 100
#define T_RAD 0.15f
#define S_RAD 0.12f

typedef __hip_bfloat16 bf16;
typedef __attribute__((ext_vector_type(8))) short short8;
typedef __attribute__((ext_vector_type(4))) float f32x4;

__device__ __forceinline__ float b2f(bf16 v) { return __bfloat162float(v); }
__device__ __forceinline__ bf16 f2b(float v) { return __float2bfloat16(v); }

__device__ __forceinline__ f32x4 mfma16(short8 a, short8 b, f32x4 c) {
    return __builtin_amdgcn_mfma_f32_16x16x32_bf16(a, b, c, 0, 0, 0);
}

// dtype-adaptive loads/stores; f: 0=f32, 1=bf16, 2=f16
__device__ __forceinline__ float load_any(const void* p, long i, int f) {
    if (f == 0) return ((const float*)p)[i];
    if (f == 1) return b2f(((const bf16*)p)[i]);
    return __half2float(((const __half*)p)[i]);
}
__device__ __forceinline__ void store_any(void* p, long i, int f, float v) {
    if (f == 0)      ((float*)p)[i] = v;
    else if (f == 1) ((bf16*)p)[i] = f2b(v);
    else             ((__half*)p)[i] = __float2half(v);
}

__device__ __forceinline__ unsigned pack2(float a, float b) {
    bf16 x = f2b(a), y = f2b(b);
    unsigned short ux = *(unsigned short*)&x, uy = *(unsigned short*)&y;
    return (unsigned)ux | ((unsigned)uy << 16);
}

// ---------------- dtype / mask-width detection (parallel) ----------------
__global__ __launch_bounds__(256) void detect_kernel(const void* __restrict__ ln1g,
                                                     const void* __restrict__ mask,
                                                     int* __restrict__ flags) {
    __shared__ int sh[6];
    int tid = threadIdx.x;
    if (tid < 6) sh[tid] = (tid == 0 || tid == 2 || tid == 4) ? 1 : 0;
    __syncthreads();
    const unsigned long long* m64 = (const unsigned long long*)mask;
    const unsigned int*       m32 = (const unsigned int*)mask;
    const unsigned short*     m16 = (const unsigned short*)mask;
    int lok8 = 1, lones8 = 0, lok4 = 1, lones4 = 0, lok2 = 1, lones2 = 0;
    for (int i = tid; i < 480; i += 256) {
        if (i < 120) {
            unsigned long long v = m64[i];
            if (v == 1ULL) lones8++; else if (v != 0ULL) lok8 = 0;
        }
        if (i < 240) {
            unsigned int v = m32[i];
            if (v == 1u || v == 0x3F800000u) lones4++; else if (v != 0u) lok4 = 0;
        }
        unsigned short v = m16[i];
        if (v == 1 || v == 0x3F80) lones2++; else if (v != 0) lok2 = 0;
    }
    atomicAnd(&sh[0], lok8); atomicAdd(&sh[1], lones8);
    atomicAnd(&sh[2], lok4); atomicAdd(&sh[3], lones4);
    atomicAnd(&sh[4], lok2); atomicAdd(&sh[5], lones2);
    __syncthreads();
    if (tid == 0) {
        unsigned short u0 = ((const unsigned short*)ln1g)[0];
        flags[0] = (u0 == 0x3F80) ? 1 : (u0 == 0x3C00 ? 2 : 0);
        int ms;
        if (sh[0] && sh[1] > 30)       ms = 8;
        else if (sh[2] && sh[3] > 60)  ms = 4;
        else if (sh[4] && sh[5] > 120) ms = 2;
        else                           ms = 1;
        flags[1] = ms;
    }
}

// ---------------- weight matrix transpose: src [R][C] -> dst [C][R] bf16 ----------------
__global__ __launch_bounds__(256) void transpose_w(const void* __restrict__ src,
                                                   bf16* __restrict__ dst, int R, int C,
                                                   const int* __restrict__ flags) {
    int i = blockIdx.x * 256 + threadIdx.x;
    if (i >= R * C) return;
    int c = i / R, r = i % R;
    dst[i] = f2b(load_any(src, (long)r * C + c, flags[0]));
}

// ---------------- batched bias/LN-param conversion -> bf16 ----------------
#define NW 14
struct WCvt {
    const void* src[NW];
    int dst_off[NW];
    int count[NW];
    int blk_start[NW + 1];
};
__global__ __launch_bounds__(256) void cvt_w_kernel(WCvt wc, bf16* __restrict__ dst,
                                                    const int* __restrict__ flags) {
    int blk = blockIdx.x;
    int a = 0;
    while (a < NW - 1 && blk >= wc.blk_start[a + 1]) a++;
    int i = (blk - wc.blk_start[a]) * 256 + threadIdx.x;
    if (i >= wc.count[a]) return;
    dst[wc.dst_off[a] + i] = f2b(load_any(wc.src[a], i, flags[0]));
}

// ---------------- image_feats (c, ch, y, x) -> imgT (c, y, x, ch) bf16 ----------------
__global__ __launch_bounds__(256) void transpose_img(const void* __restrict__ in,
                                                     bf16* __restrict__ out,
                                                     const int* __restrict__ flags) {
    int i = blockIdx.x * 256 + threadIdx.x;
    if (i >= NC * HF * WF * 256) return;
    int ch = i & 255;
    int t = i >> 8;
    int xx = t % WF; t /= WF;
    int yy = t % HF;
    int c  = t / HF;
    long src = (((long)(c * 256) + ch) * HF + yy) * WF + xx;
    out[i] = f2b(load_any(in, src, flags[0]));
}

// ---------------- LN1 over both prev_bev and query -> ai[N,512] ----------------
__global__ __launch_bounds__(256) void ln12_kernel(const void* __restrict__ pb,
                                                   const void* __restrict__ q,
                                                   const int* __restrict__ flags,
                                                   const bf16* __restrict__ g,
                                                   const bf16* __restrict__ b,
                                                   bf16* __restrict__ out) {
    int n = blockIdx.x, tid = threadIdx.x;
    const void* src; int row, ooff;
    if (n < N_Q) { src = pb; row = n; ooff = 0; }
    else         { src = q;  row = n - N_Q; ooff = 256; }
    float v = load_any(src, (long)row * D_MODEL + tid, flags[0]);
    __shared__ float red[D_MODEL];
    red[tid] = v; __syncthreads();
    #pragma unroll
    for (int s = 128; s > 0; s >>= 1) { if (tid < s) red[tid] += red[tid + s]; __syncthreads(); }
    float mu = red[0] * (1.f / D_MODEL); __syncthreads();
    float d = v - mu;
    red[tid] = d * d; __syncthreads();
    #pragma unroll
    for (int s = 128; s > 0; s >>= 1) { if (tid < s) red[tid] += red[tid + s]; __syncthreads(); }
    float var = red[0] * (1.f / D_MODEL);
    out[(long)row * 512 + ooff + tid] = f2b(d * rsqrtf(var + 1e-5f) * b2f(g[tid]) + b2f(b[tid]));
}

// ---------------- LayerNorm (f32 in) over D=256, one row per block -> bf16 out ----------------
__global__ __launch_bounds__(256) void ln_kernel(const float* __restrict__ in,
                                                 const bf16* __restrict__ g,
                                                 const bf16* __restrict__ b,
                                                 bf16* __restrict__ out) {
    int n = blockIdx.x, tid = threadIdx.x;
    float v = in[(long)n * D_MODEL + tid];
    __shared__ float red[D_MODEL];
    red[tid] = v; __syncthreads();
    #pragma unroll
    for (int s = 128; s > 0; s >>= 1) { if (tid < s) red[tid] += red[tid + s]; __syncthreads(); }
    float mu = red[0] * (1.f / D_MODEL); __syncthreads();
    float d = v - mu;
    red[tid] = d * d; __syncthreads();
    #pragma unroll
    for (int s = 128; s > 0; s >>= 1) { if (tid < s) red[tid] += red[tid + s]; __syncthreads(); }
    float var = red[0] * (1.f / D_MODEL);
    out[(long)n * D_MODEL + tid] = f2b(d * rsqrtf(var + 1e-5f) * b2f(g[tid]) + b2f(b[tid]));
}

// ---------------- MFMA GEMM: out[M,J] = A[M,K](bf16) @ WT[J,K]^T + bias ----------------
// Modes: 2 + raw residual ->f32; 3 + f32 residual ->f32.
template <int K, int J, int MODE>
__global__ __launch_bounds__(256) void gemm_mfma(const bf16* __restrict__ A,
                                                 const bf16* __restrict__ WT,
                                                 const bf16* __restrict__ bias,
                                                 float* __restrict__ outf,
                                                 const void* __restrict__ resraw,
                                                 const float* __restrict__ resf,
                                                 const int* __restrict__ flags) {
    constexpr int MT = 32;
    constexpr int LDK = K + 8;
    __shared__ bf16 As[MT * LDK];
    int tid = threadIdx.x;
    int row0 = blockIdx.x * MT;
    for (int t = tid; t < MT * (K / 8); t += 256) {
        int r = t / (K / 8), kq = t % (K / 8);
        uint4 u = {0u, 0u, 0u, 0u};
        if (row0 + r < N_Q)
            u = *reinterpret_cast<const uint4*>(A + (size_t)(row0 + r) * K + kq * 8);
        *reinterpret_cast<uint4*>(&As[r * LDK + kq * 8]) = u;
    }
    __syncthreads();
    int wave = tid >> 6, lane = tid & 63;
    int l = lane & 15, quad = lane >> 4;
    int rh = wave >> 1, chalf = wave & 1;
    constexpr int NK = K / 32;
    constexpr int NCT = J / 32;
    short8 afr[NK];
    const bf16* arow = &As[(rh * 16 + l) * LDK + quad * 8];
    #pragma unroll
    for (int ks = 0; ks < NK; ks++)
        afr[ks] = *reinterpret_cast<const short8*>(arow + ks * 32);
    int fdt = flags[0];
    for (int ct = 0; ct < NCT; ct++) {
        int col = chalf * (J / 2) + ct * 16 + l;
        const bf16* wrow = WT + (size_t)col * K + quad * 8;
        f32x4 acc = {0.f, 0.f, 0.f, 0.f};
        #pragma unroll
        for (int ks = 0; ks < NK; ks++) {
            short8 bfr = *reinterpret_cast<const short8*>(wrow + ks * 32);
            acc = mfma16(afr[ks], bfr, acc);
        }
        float bb = b2f(bias[col]);
        #pragma unroll
        for (int r = 0; r < 4; r++) {
            int row = row0 + rh * 16 + quad * 4 + r;
            if (row >= N_Q) continue;
            long o = (long)row * J + col;
            float v = acc[r] + bb;
            if (MODE == 2) outf[o] = v + load_any(resraw, o, fdt);
            else           outf[o] = v + resf[o];
        }
    }
}

// ---------------- Dual MFMA GEMM: same A, two weight mats; out1=tanh(v)*scale, out2=plain ----
template <int K, int J1, int J2>
__global__ __launch_bounds__(256) void gemm_dual(const bf16* __restrict__ A,
                                                 const bf16* __restrict__ WT1,
                                                 const bf16* __restrict__ b1, float scale,
                                                 bf16* __restrict__ out1,
                                                 const bf16* __restrict__ WT2,
                                                 const bf16* __restrict__ b2,
                                                 bf16* __restrict__ out2) {
    constexpr int MT = 32;
    constexpr int LDK = K + 8;
    __shared__ bf16 As[MT * LDK];
    int tid = threadIdx.x;
    int row0 = blockIdx.x * MT;
    for (int t = tid; t < MT * (K / 8); t += 256) {
        int r = t / (K / 8), kq = t % (K / 8);
        uint4 u = {0u, 0u, 0u, 0u};
        if (row0 + r < N_Q)
            u = *reinterpret_cast<const uint4*>(A + (size_t)(row0 + r) * K + kq * 8);
        *reinterpret_cast<uint4*>(&As[r * LDK + kq * 8]) = u;
    }
    __syncthreads();
    int wave = tid >> 6, lane = tid & 63;
    int l = lane & 15, quad = lane >> 4;
    int rh = wave >> 1, chalf = wave & 1;
    constexpr int NK = K / 32;
    constexpr int NT = (J1 + J2) / 16;
    short8 afr[NK];
    const bf16* arow = &As[(rh * 16 + l) * LDK + quad * 8];
    #pragma unroll
    for (int ks = 0; ks < NK; ks++)
        afr[ks] = *reinterpret_cast<const short8*>(arow + ks * 32);
    for (int ct = chalf; ct < NT; ct += 2) {
        int colg = ct * 16 + l;
        int in1 = (ct * 16 < J1);
        int col = in1 ? colg : colg - J1;
        const bf16* wrow = (in1 ? WT1 : WT2) + (size_t)col * K + quad * 8;
        f32x4 acc = {0.f, 0.f, 0.f, 0.f};
        #pragma unroll
        for (int ks = 0; ks < NK; ks++) {
            short8 bfr = *reinterpret_cast<const short8*>(wrow + ks * 32);
            acc = mfma16(afr[ks], bfr, acc);
        }
        float bb = b2f(in1 ? b1[col] : b2[col]);
        #pragma unroll
        for (int r = 0; r < 4; r++) {
            int row = row0 + rh * 16 + quad * 4 + r;
            if (row >= N_Q) continue;
            float v = acc[r] + bb;
            if (in1) out1[(long)row * J1 + col] = f2b(tanhf(v) * scale);
            else     out2[(long)row * J2 + col] = f2b(v);
        }
    }
}

// ---------------- Fused MFMA FFN: LN3 -> @w1T,relu -> @w2T -> +x -> out ----------------
__global__ __launch_bounds__(256) void ffn_mfma(const float* __restrict__ x,
                                                const bf16* __restrict__ g3,
                                                const bf16* __restrict__ b3,
                                                const bf16* __restrict__ w1T,  // [1024][256]
                                                const bf16* __restrict__ b1,
                                                const bf16* __restrict__ w2T,  // [256][1024]
                                                const bf16* __restrict__ b2v,
                                                void* __restrict__ out,
                                                const int* __restrict__ flags) {
    constexpr int LDH = DFF + 8;
    constexpr int LDX = D_MODEL + 8;
    __shared__ bf16 hbuf[16 * LDH];
    bf16* xl = hbuf;
    int tid = threadIdx.x;
    int row0 = blockIdx.x * 16;
    {
        int r = tid >> 4, lr = tid & 15;
        const float* xr = x + (long)(row0 + r) * 256 + lr * 16;
        float vals[16];
        float s1 = 0.f, s2 = 0.f;
        #pragma unroll
        for (int i = 0; i < 16; i++) {
            float v = xr[i];
            vals[i] = v; s1 += v; s2 += v * v;
        }
        #pragma unroll
        for (int off = 8; off > 0; off >>= 1) {
            s1 += __shfl_down(s1, off, 16);
            s2 += __shfl_down(s2, off, 16);
        }
        s1 = __shfl(s1, 0, 16);
        s2 = __shfl(s2, 0, 16);
        float mu = s1 * (1.f / 256.f);
        float var = s2 * (1.f / 256.f) - mu * mu;
        float inv = rsqrtf(var + 1e-5f);
        #pragma unroll
        for (int i = 0; i < 16; i++) {
            int k = lr * 16 + i;
            xl[r * LDX + k] = f2b((vals[i] - mu) * inv * b2f(g3[k]) + b2f(b3[k]));
        }
    }
    __syncthreads();
    int wave = tid >> 6, lane = tid & 63;
    int l = lane & 15, quad = lane >> 4;
    short8 afr[8];
    {
        const bf16* arow = xl + l * LDX + quad * 8;
        #pragma unroll
        for (int ks = 0; ks < 8; ks++)
            afr[ks] = *reinterpret_cast<const short8*>(arow + ks * 32);
    }
    __syncthreads();
    for (int ct = 0; ct < 16; ct++) {
        int col = wave * 256 + ct * 16 + l;
        const bf16* wrow = w1T + (size_t)col * 256 + quad * 8;
        f32x4 acc = {0.f, 0.f, 0.f, 0.f};
        #pragma unroll
        for (int ks = 0; ks < 8; ks++) {
            short8 bfr = *reinterpret_cast<const short8*>(wrow + ks * 32);
            acc = mfma16(afr[ks], bfr, acc);
        }
        float bb = b2f(b1[col]);
        #pragma unroll
        for (int r = 0; r < 4; r++)
            hbuf[(quad * 4 + r) * LDH + col] = f2b(fmaxf(acc[r] + bb, 0.f));
    }
    __syncthreads();
    int fdt = flags[0];
    for (int ct = 0; ct < 4; ct++) {
        int col = wave * 64 + ct * 16 + l;
        const bf16* wrow = w2T + (size_t)col * 1024 + quad * 8;
        const bf16* hrow = hbuf + l * LDH + quad * 8;
        f32x4 acc = {0.f, 0.f, 0.f, 0.f};
        #pragma unroll 8
        for (int ks = 0; ks < 32; ks++) {
            short8 a2 = *reinterpret_cast<const short8*>(hrow + ks * 32);
            short8 bfr = *reinterpret_cast<const short8*>(wrow + ks * 32);
            acc = mfma16(a2, bfr, acc);
        }
        float bb = b2f(b2v[col]);
        #pragma unroll
        for (int r = 0; r < 4; r++) {
            long o = (long)(row0 + quad * 4 + r) * 256 + col;
            store_any(out, o, fdt, x[o] + acc[r] + bb);
        }
    }
}

// ---------------- Temporal deformable sampling (8 queries/block, 8 ch/thread) ----------------
__global__ __launch_bounds__(256) void temporal_kernel(const bf16* __restrict__ ai,
                                                       const bf16* __restrict__ toffB,
                                                       const bf16* __restrict__ twlB,
                                                       const void* __restrict__ ref2d,
                                                       const void* __restrict__ ego,
                                                       const int* __restrict__ flags,
                                                       bf16* __restrict__ tfB) {
    int tid = threadIdx.x;
    int ql = tid >> 5, t = tid & 31;
    int g = t >> 2, q4 = t & 3;
    long n0 = (long)blockIdx.x * 8;
    __shared__ float s_toff[8][8][17];
    __shared__ float s_twl[8][64];
    __shared__ float s_base[8][4];
    for (int i = tid; i < 8 * 128; i += 256) {
        int q = i >> 7, j = i & 127;
        int si = j >> 6, r = j & 63, gg = r >> 3, w = r & 7;
        s_toff[q][gg][si * 8 + w] = b2f(toffB[n0 * 128 + i]);
    }
    for (int i = tid; i < 8 * 64; i += 256) s_twl[i >> 6][i & 63] = b2f(twlB[n0 * 64 + i]);
    if (tid < 8) {
        int f = flags[0];
        float rx = load_any(ref2d, (n0 + tid) * 2, f), ry = load_any(ref2d, (n0 + tid) * 2 + 1, f);
        s_base[tid][0] = rx + load_any(ego, 0, f); s_base[tid][1] = ry + load_any(ego, 1, f);
        s_base[tid][2] = rx;                       s_base[tid][3] = ry;
    }
    __syncthreads();
    float acc[8];
    #pragma unroll
    for (int i = 0; i < 8; i++) acc[i] = 0.f;
    int choff = g * 32 + q4 * 8;
    #pragma unroll
    for (int si = 0; si < 2; si++) {
        float l0 = s_twl[ql][si * 32 + g * 4 + 0], l1 = s_twl[ql][si * 32 + g * 4 + 1];
        float l2 = s_twl[ql][si * 32 + g * 4 + 2], l3 = s_twl[ql][si * 32 + g * 4 + 3];
        float mx = fmaxf(fmaxf(l0, l1), fmaxf(l2, l3));
        float e0 = __expf(l0 - mx), e1 = __expf(l1 - mx);
        float e2 = __expf(l2 - mx), e3 = __expf(l3 - mx);
        float inv = 1.f / (e0 + e1 + e2 + e3);
        float wts[4] = {e0 * inv, e1 * inv, e2 * inv, e3 * inv};
        int aoff = si * 256;
        float bx = s_base[ql][si * 2], by = s_base[ql][si * 2 + 1];
        #pragma unroll
        for (int pt = 0; pt < 4; pt++) {
            float u = bx + s_toff[ql][g][si * 8 + pt * 2 + 0];
            float v = by + s_toff[ql][g][si * 8 + pt * 2 + 1];
            float ix = u * (float)BW - 0.5f;
            float iy = v * (float)BH - 0.5f;
            float x0f = floorf(ix), y0f = floorf(iy);
            int x0 = (int)x0f, y0 = (int)y0f;
            float wx1 = ix - x0f, wy1 = iy - y0f;
            float wx0 = 1.f - wx1, wy0 = 1.f - wy1;
            #pragma unroll
            for (int cy = 0; cy < 2; cy++) {
                int yy = y0 + cy;
                if ((unsigned)yy >= BH) continue;
                float wy = cy ? wy1 : wy0;
                #pragma unroll
                for (int cx = 0; cx < 2; cx++) {
                    int xx = x0 + cx;
                    if ((unsigned)xx >= BW) continue;
                    float wq = wts[pt] * wy * (cx ? wx1 : wx0);
                    uint4 uu = *reinterpret_cast<const uint4*>(
                        ai + (long)(yy * BW + xx) * 512 + aoff + choff);
                    acc[0] += wq * __uint_as_float(uu.x << 16);
                    acc[1] += wq * __uint_as_float(uu.x & 0xFFFF0000u);
                    acc[2] += wq * __uint_as_float(uu.y << 16);
                    acc[3] += wq * __uint_as_float(uu.y & 0xFFFF0000u);
                    acc[4] += wq * __uint_as_float(uu.z << 16);
                    acc[5] += wq * __uint_as_float(uu.z & 0xFFFF0000u);
                    acc[6] += wq * __uint_as_float(uu.w << 16);
                    acc[7] += wq * __uint_as_float(uu.w & 0xFFFF0000u);
                }
            }
        }
    }
    uint4 o;
    o.x = pack2(acc[0] * 0.5f, acc[1] * 0.5f);
    o.y = pack2(acc[2] * 0.5f, acc[3] * 0.5f);
    o.z = pack2(acc[4] * 0.5f, acc[5] * 0.5f);
    o.w = pack2(acc[6] * 0.5f, acc[7] * 0.5f);
    *reinterpret_cast<uint4*>(tfB + (n0 + ql) * 256 + choff) = o;
}

// ---------------- Spatial sampling v3: 4 queries/block x 32 thr, softmax in regs ----------------
__global__ __launch_bounds__(128) void spatial_kernel(const bf16* __restrict__ soffB,
                                                      const bf16* __restrict__ swlB,
                                                      const void* __restrict__ refcam,
                                                      const void* __restrict__ bmask,
                                                      const bf16* __restrict__ imgT,
                                                      const void* __restrict__ img_raw,
                                                      int use_imgT,
                                                      const int* __restrict__ flags,
                                                      bf16* __restrict__ sfB) {
    int tid = threadIdx.x;
    int ql = tid >> 5, t = tid & 31;
    int g = t >> 2, q4 = t & 3;
    long n0 = (long)blockIdx.x * 4;
    __shared__ float s_soff[4][8][33];
    __shared__ float s_swl[4][128];
    __shared__ float s_ref[4][NC][PP][2];
    __shared__ int   s_vis[4][NC][PP];
    for (int i = tid; i < 4 * 256; i += 128) {
        int q = i >> 8, j = i & 255;
        s_soff[q][j >> 5][j & 31] = b2f(soffB[n0 * 256 + i]);
    }
    for (int i = tid; i < 4 * 128; i += 128) s_swl[i >> 7][i & 127] = b2f(swlB[n0 * 128 + i]);
    int fdt = flags[0], msz = flags[1];
    for (int i = tid; i < 4 * 48; i += 128) {
        int q = i / 48, r = i % 48;
        s_ref[q][r >> 3][(r & 7) >> 1][r & 1] =
            load_any(refcam, ((long)(r >> 3) * N_Q + n0 + q) * 8 + (r & 7), fdt);
    }
    if (tid < 4 * 24) {
        int q = tid / 24, r = tid % 24; int c = r >> 2, p = r & 3;
        long idx = ((long)c * N_Q + n0 + q) * 4 + p;
        int v;
        if (msz == 1)      v = ((const unsigned char*)bmask)[idx] != 0;
        else if (msz == 2) v = ((const unsigned short*)bmask)[idx] != 0;
        else if (msz == 4) v = ((const unsigned int*)bmask)[idx] != 0u;
        else               v = ((const unsigned long long*)bmask)[idx] != 0ULL;
        s_vis[q][c][p] = v;
    }
    __syncthreads();
    float acc[8];
    #pragma unroll
    for (int i = 0; i < 8; i++) acc[i] = 0.f;
    float cnt = 0.f;
    int choff = g * 32 + q4 * 8;
    for (int c = 0; c < NC; c++) {
        if (!(s_vis[ql][c][0] | s_vis[ql][c][1] | s_vis[ql][c][2] | s_vis[ql][c][3])) continue;
        cnt += 1.f;
        // per-thread masked softmax over 16 (broadcast LDS reads; q4 lanes redundant)
        float w[16], mx = -3e38f;
        #pragma unroll
        for (int j = 0; j < 16; j++) {
            float li = s_vis[ql][c][j >> 2] ? s_swl[ql][g * 16 + j] : -3e38f;
            w[j] = li; mx = fmaxf(mx, li);
        }
        float sum = 0.f;
        #pragma unroll
        for (int j = 0; j < 16; j++) {
            float e = (w[j] > -1e37f) ? __expf(w[j] - mx) : 0.f;
            w[j] = e; sum += e;
        }
        float inv = 1.f / fmaxf(sum, 1e-20f);
        const bf16* img = imgT + (long)c * HF * WF * 256 + choff;
        #pragma unroll
        for (int p = 0; p < PP; p++) {
            if (!s_vis[ql][c][p]) continue;
            float rx = s_ref[ql][c][p][0], ry = s_ref[ql][c][p][1];
            #pragma unroll
            for (int s = 0; s < PS; s++) {
                float wi = w[p * 4 + s] * inv;
                float u = rx + s_soff[ql][g][p * 8 + s * 2 + 0];
                float v = ry + s_soff[ql][g][p * 8 + s * 2 + 1];
                float ix = u * (float)WF - 0.5f, iy = v * (float)HF - 0.5f;
                float x0f = floorf(ix), y0f = floorf(iy);
                int x0 = (int)x0f, y0 = (int)y0f;
                float wx1 = ix - x0f, wy1 = iy - y0f;
                float wx0 = 1.f - wx1, wy0 = 1.f - wy1;
                #pragma unroll
                for (int cy = 0; cy < 2; cy++) {
                    int yy = y0 + cy;
                    if ((unsigned)yy >= HF) continue;
                    float wy = cy ? wy1 : wy0;
                    #pragma unroll
                    for (int cx = 0; cx < 2; cx++) {
                        int xx = x0 + cx;
                        if ((unsigned)xx >= WF) continue;
                        float wq = wi * wy * (cx ? wx1 : wx0);
                        if (use_imgT) {
                            uint4 uu = *reinterpret_cast<const uint4*>(img + (long)(yy * WF + xx) * 256);
                            acc[0] += wq * __uint_as_float(uu.x << 16);
                            acc[1] += wq * __uint_as_float(uu.x & 0xFFFF0000u);
                            acc[2] += wq * __uint_as_float(uu.y << 16);
                            acc[3] += wq * __uint_as_float(uu.y & 0xFFFF0000u);
                            acc[4] += wq * __uint_as_float(uu.z << 16);
                            acc[5] += wq * __uint_as_float(uu.z & 0xFFFF0000u);
                            acc[6] += wq * __uint_as_float(uu.w << 16);
                            acc[7] += wq * __uint_as_float(uu.w & 0xFFFF0000u);
                        } else {
                            #pragma unroll
                            for (int e = 0; e < 8; e++)
                                acc[e] += wq * load_any(img_raw,
                                    (((long)c * 256 + choff + e) * HF + yy) * WF + xx, fdt);
                        }
                    }
                }
            }
        }
    }
    float invc = 1.f / fmaxf(cnt, 1.f);
    uint4 o;
    o.x = pack2(acc[0] * invc, acc[1] * invc);
    o.y = pack2(acc[2] * invc, acc[3] * invc);
    o.z = pack2(acc[4] * invc, acc[5] * invc);
    o.w = pack2(acc[6] * invc, acc[7] * invc);
    *reinterpret_cast<uint4*>(sfB + (n0 + ql) * 256 + choff) = o;
}

// bf16 element offsets inside the weight region (matrices stored TRANSPOSED [J][K])
#define W_TOFF_W 0
#define W_TOFF_B 65536
#define W_TWT_W  65664
#define W_TWT_B  98432
#define W_TOUT_W 98496
#define W_TOUT_B 164032
#define W_SOFF_W 164288
#define W_SOFF_B 229824
#define W_SWT_W  230080
#define W_SWT_B  262848
#define W_SOUT_W 262976
#define W_SOUT_B 328512
#define W_FFN_W1 328768
#define W_FFN_B1 590912
#define W_FFN_W2 591936
#define W_FFN_B2 854080
#define W_LN1_G  854336
#define W_LN1_B  854592
#define W_LN2_G  854848
#define W_LN2_B  855104
#define W_LN3_G  855360
#define W_LN3_B  855616

// byte offsets in workspace (total ~35.6 MB)
#define OB_WGT   0
#define OB_FLAGS 1711744
#define OB_AI    1712640
#define OB_TF    11952640
#define OB_X     17072640
#define OB_T4    27312640
#define OB_IMG   31152640
#define WS_NEED_IMG 35576320ULL

extern "C" void kernel_launch(void* const* d_in, const int* in_sizes, int n_in,
                              void* d_out, int out_size, void* d_ws, size_t ws_size,
                              hipStream_t stream) {
    char* W8 = (char*)d_ws;
    bf16*  wgt   = (bf16*)(W8 + OB_WGT);
    int*   flags = (int*)(W8 + OB_FLAGS);
    bf16*  ai    = (bf16*)(W8 + OB_AI);                 // N x 512, pb | q1
    bf16*  q2B   = ai;                                  // N x 256 (after temporal)
    bf16*  sfB   = (bf16*)(W8 + OB_AI + 5120000);       // N x 256
    bf16*  tfB   = (bf16*)(W8 + OB_TF);                 // N x 256
    bf16*  soffB = tfB;                                 // N x 256 (after t_out gemm)
    float* x     = (float*)(W8 + OB_X);                 // N x 256 f32 trunk
    bf16*  toffB = (bf16*)(W8 + OB_T4);                 // N x 128
    bf16*  twlB  = (bf16*)(W8 + OB_T4 + 2560000);       // N x 64
    bf16*  swlB  = toffB;                               // N x 128 (after temporal)
    bf16*  imgT  = (bf16*)(W8 + OB_IMG);                // NC*HF*WF*256
    int use_imgT = (ws_size >= WS_NEED_IMG) ? 1 : 0;

    detect_kernel<<<1, 256, 0, stream>>>(d_in[22], d_in[28], flags);

    transpose_w<<<256, 256, 0, stream>>>(d_in[6],  wgt + W_TOFF_W, 512, 128, flags);
    transpose_w<<<128, 256, 0, stream>>>(d_in[8],  wgt + W_TWT_W,  512, 64,  flags);
    transpose_w<<<256, 256, 0, stream>>>(d_in[10], wgt + W_TOUT_W, 256, 256, flags);
    transpose_w<<<256, 256, 0, stream>>>(d_in[12], wgt + W_SOFF_W, 256, 256, flags);
    transpose_w<<<128, 256, 0, stream>>>(d_in[14], wgt + W_SWT_W,  256, 128, flags);
    transpose_w<<<256, 256, 0, stream>>>(d_in[16], wgt + W_SOUT_W, 256, 256, flags);
    transpose_w<<<1024, 256, 0, stream>>>(d_in[18], wgt + W_FFN_W1, 256, 1024, flags);
    transpose_w<<<1024, 256, 0, stream>>>(d_in[20], wgt + W_FFN_W2, 1024, 256, flags);

    {   // biases + LN params -> bf16 flat
        WCvt wc;
        const int srcs[NW] = {7,9,11,13,15,17,19,21,22,23,24,25,26,27};
        const int offs[NW] = {W_TOFF_B,W_TWT_B,W_TOUT_B,W_SOFF_B,W_SWT_B,W_SOUT_B,
                              W_FFN_B1,W_FFN_B2,W_LN1_G,W_LN1_B,W_LN2_G,W_LN2_B,W_LN3_G,W_LN3_B};
        const int cnts[NW] = {128,64,256,256,128,256,1024,256,256,256,256,256,256,256};
        int blk = 0;
        for (int a = 0; a < NW; a++) {
            wc.src[a] = d_in[srcs[a]];
            wc.dst_off[a] = offs[a];
            wc.count[a] = cnts[a];
            wc.blk_start[a] = blk;
            blk += (cnts[a] + 255) / 256;
        }
        wc.blk_start[NW] = blk;
        cvt_w_kernel<<<blk, 256, 0, stream>>>(wc, wgt, flags);
    }

    ln12_kernel<<<2 * N_Q, 256, 0, stream>>>(d_in[1], d_in[0], flags,
                                             wgt + W_LN1_G, wgt + W_LN1_B, ai);
    gemm_dual<512, 128, 64><<<313, 256, 0, stream>>>(ai,
        wgt + W_TOFF_W, wgt + W_TOFF_B, T_RAD, toffB,
        wgt + W_TWT_W, wgt + W_TWT_B, twlB);
    temporal_kernel<<<1250, 256, 0, stream>>>(ai, toffB, twlB, d_in[3], d_in[5], flags, tfB);
    gemm_mfma<256, 256, 2><<<313, 256, 0, stream>>>(tfB, wgt + W_TOUT_W, wgt + W_TOUT_B,
        x, d_in[0], nullptr, flags);
    ln_kernel<<<N_Q, 256, 0, stream>>>(x, wgt + W_LN2_G, wgt + W_LN2_B, q2B);
    gemm_dual<256, 256, 128><<<313, 256, 0, stream>>>(q2B,
        wgt + W_SOFF_W, wgt + W_SOFF_B, S_RAD, soffB,
        wgt + W_SWT_W, wgt + W_SWT_B, swlB);
    if (use_imgT)
        transpose_img<<<8640, 256, 0, stream>>>(d_in[2], imgT, flags);
    spatial_kernel<<<2500, 128, 0, stream>>>(soffB, swlB, d_in[4], d_in[28], imgT, d_in[2],
                                             use_imgT, flags, sfB);
    gemm_mfma<256, 256, 3><<<313, 256, 0, stream>>>(sfB, wgt + W_SOUT_W, wgt + W_SOUT_B,
        x, nullptr, x, flags);
    ffn_mfma<<<625, 256, 0, stream>>>(x, wgt + W_LN3_G, wgt + W_LN3_B,
                                      wgt + W_FFN_W1, wgt + W_FFN_B1,
                                      wgt + W_FFN_W2, wgt + W_FFN_B2, d_out, flags);
}

// Round 7
// 567.577 us; speedup vs baseline: 2.2524x; 1.0066x over previous
//
#include <hip/hip_runtime.h>
#include <hip/hip_bf16.h>
#include <hip/hip_fp16.h>

#define N_Q 10000
#define D_MODEL 256
#define NH 8
#define PT 4
#define PP 4
#define PS 4
#define DFF 1024
#define NC 6
#define HF 24
#define WF 60
#define BH 100
#define BW 100
#define T_RAD 0.15f
#define S_RAD 0.12f

typedef __hip_bfloat16 bf16;
typedef __attribute__((ext_vector_type(8))) short short8;
typedef __attribute__((ext_vector_type(4))) float f32x4;

__device__ __forceinline__ float b2f(bf16 v) { return __bfloat162float(v); }
__device__ __forceinline__ bf16 f2b(float v) { return __float2bfloat16(v); }

__device__ __forceinline__ f32x4 mfma16(short8 a, short8 b, f32x4 c) {
    return __builtin_amdgcn_mfma_f32_16x16x32_bf16(a, b, c, 0, 0, 0);
}

// dtype-adaptive loads/stores; f: 0=f32, 1=bf16, 2=f16
__device__ __forceinline__ float load_any(const void* p, long i, int f) {
    if (f == 0) return ((const float*)p)[i];
    if (f == 1) return b2f(((const bf16*)p)[i]);
    return __half2float(((const __half*)p)[i]);
}
__device__ __forceinline__ void store_any(void* p, long i, int f, float v) {
    if (f == 0)      ((float*)p)[i] = v;
    else if (f == 1) ((bf16*)p)[i] = f2b(v);
    else             ((__half*)p)[i] = __float2half(v);
}

__device__ __forceinline__ unsigned pack2(float a, float b) {
    bf16 x = f2b(a), y = f2b(b);
    unsigned short ux = *(unsigned short*)&x, uy = *(unsigned short*)&y;
    return (unsigned)ux | ((unsigned)uy << 16);
}

// ---------------- dtype / mask-width detection (parallel) ----------------
__global__ __launch_bounds__(256) void detect_kernel(const void* __restrict__ ln1g,
                                                     const void* __restrict__ mask,
                                                     int* __restrict__ flags) {
    __shared__ int sh[6];
    int tid = threadIdx.x;
    if (tid < 6) sh[tid] = (tid == 0 || tid == 2 || tid == 4) ? 1 : 0;
    __syncthreads();
    const unsigned long long* m64 = (const unsigned long long*)mask;
    const unsigned int*       m32 = (const unsigned int*)mask;
    const unsigned short*     m16 = (const unsigned short*)mask;
    int lok8 = 1, lones8 = 0, lok4 = 1, lones4 = 0, lok2 = 1, lones2 = 0;
    for (int i = tid; i < 480; i += 256) {
        if (i < 120) {
            unsigned long long v = m64[i];
            if (v == 1ULL) lones8++; else if (v != 0ULL) lok8 = 0;
        }
        if (i < 240) {
            unsigned int v = m32[i];
            if (v == 1u || v == 0x3F800000u) lones4++; else if (v != 0u) lok4 = 0;
        }
        unsigned short v = m16[i];
        if (v == 1 || v == 0x3F80) lones2++; else if (v != 0) lok2 = 0;
    }
    atomicAnd(&sh[0], lok8); atomicAdd(&sh[1], lones8);
    atomicAnd(&sh[2], lok4); atomicAdd(&sh[3], lones4);
    atomicAnd(&sh[4], lok2); atomicAdd(&sh[5], lones2);
    __syncthreads();
    if (tid == 0) {
        unsigned short u0 = ((const unsigned short*)ln1g)[0];
        flags[0] = (u0 == 0x3F80) ? 1 : (u0 == 0x3C00 ? 2 : 0);
        int ms;
        if (sh[0] && sh[1] > 30)       ms = 8;
        else if (sh[2] && sh[3] > 60)  ms = 4;
        else if (sh[4] && sh[5] > 120) ms = 2;
        else                           ms = 1;
        flags[1] = ms;
    }
}

// ---------------- unified weight/image prep: transposes + flat cvt + img transpose ----------------
#define NP 23
struct PrepDesc {
    const void* src[NP];
    int dst_off[NP];
    int count[NP];
    int R[NP];
    int C[NP];
    int type[NP];       // 0 flat cvt, 1 transpose, 2 img transpose
    int blk_start[NP + 1];
};
__global__ __launch_bounds__(256) void prep_kernel(PrepDesc pd, bf16* __restrict__ wgt,
                                                   bf16* __restrict__ imgT,
                                                   const int* __restrict__ flags) {
    int blk = blockIdx.x;
    int a = 0;
    while (a < NP - 1 && blk >= pd.blk_start[a + 1]) a++;
    int i = (blk - pd.blk_start[a]) * 256 + threadIdx.x;
    if (i >= pd.count[a]) return;
    int f = flags[0];
    int ty = pd.type[a];
    if (ty == 0) {
        wgt[pd.dst_off[a] + i] = f2b(load_any(pd.src[a], i, f));
    } else if (ty == 1) {
        int R = pd.R[a], C = pd.C[a];
        int c = i / R, r = i % R;
        wgt[pd.dst_off[a] + i] = f2b(load_any(pd.src[a], (long)r * C + c, f));
    } else {
        int ch = i & 255;
        int t = i >> 8;
        int xx = t % WF; t /= WF;
        int yy = t % HF;
        int c  = t / HF;
        long src = (((long)(c * 256) + ch) * HF + yy) * WF + xx;
        imgT[i] = f2b(load_any(pd.src[a], src, f));
    }
}

// ---------------- LN1 over prev_bev & query, wave-per-row -> ai[N,512] ----------------
__global__ __launch_bounds__(256) void ln12_kernel(const void* __restrict__ pb,
                                                   const void* __restrict__ q,
                                                   const int* __restrict__ flags,
                                                   const bf16* __restrict__ g,
                                                   const bf16* __restrict__ b,
                                                   bf16* __restrict__ out) {
    int wv = threadIdx.x >> 6, lane = threadIdx.x & 63;
    long row = (long)blockIdx.x * 4 + wv;
    const void* src; long r; int ooff;
    if (row < N_Q) { src = pb; r = row; ooff = 0; }
    else           { src = q;  r = row - N_Q; ooff = 256; }
    int f = flags[0];
    float v0, v1, v2, v3;
    if (f == 0) {
        float4 t = ((const float4*)src)[r * 64 + lane];
        v0 = t.x; v1 = t.y; v2 = t.z; v3 = t.w;
    } else {
        uint2 t = ((const uint2*)src)[r * 64 + lane];
        if (f == 1) {
            v0 = __uint_as_float(t.x << 16); v1 = __uint_as_float(t.x & 0xFFFF0000u);
            v2 = __uint_as_float(t.y << 16); v3 = __uint_as_float(t.y & 0xFFFF0000u);
        } else {
            __half2 h0 = *(__half2*)&t.x, h1 = *(__half2*)&t.y;
            v0 = __half2float(h0.x); v1 = __half2float(h0.y);
            v2 = __half2float(h1.x); v3 = __half2float(h1.y);
        }
    }
    float s1 = v0 + v1 + v2 + v3;
    float s2 = v0 * v0 + v1 * v1 + v2 * v2 + v3 * v3;
    #pragma unroll
    for (int m = 32; m > 0; m >>= 1) {
        s1 += __shfl_xor(s1, m);
        s2 += __shfl_xor(s2, m);
    }
    float mu = s1 * (1.f / 256.f);
    float var = s2 * (1.f / 256.f) - mu * mu;
    float inv = rsqrtf(var + 1e-5f);
    int k = lane * 4;
    float o0 = (v0 - mu) * inv * b2f(g[k+0]) + b2f(b[k+0]);
    float o1 = (v1 - mu) * inv * b2f(g[k+1]) + b2f(b[k+1]);
    float o2 = (v2 - mu) * inv * b2f(g[k+2]) + b2f(b[k+2]);
    float o3 = (v3 - mu) * inv * b2f(g[k+3]) + b2f(b[k+3]);
    uint2 st = {pack2(o0, o1), pack2(o2, o3)};
    *reinterpret_cast<uint2*>(out + r * 512 + ooff + k) = st;
}

// ---------------- LayerNorm (f32 in), wave-per-row -> bf16 out ----------------
__global__ __launch_bounds__(256) void ln_kernel(const float* __restrict__ in,
                                                 const bf16* __restrict__ g,
                                                 const bf16* __restrict__ b,
                                                 bf16* __restrict__ out) {
    int wv = threadIdx.x >> 6, lane = threadIdx.x & 63;
    long r = (long)blockIdx.x * 4 + wv;
    float4 t = ((const float4*)in)[r * 64 + lane];
    float s1 = t.x + t.y + t.z + t.w;
    float s2 = t.x * t.x + t.y * t.y + t.z * t.z + t.w * t.w;
    #pragma unroll
    for (int m = 32; m > 0; m >>= 1) {
        s1 += __shfl_xor(s1, m);
        s2 += __shfl_xor(s2, m);
    }
    float mu = s1 * (1.f / 256.f);
    float var = s2 * (1.f / 256.f) - mu * mu;
    float inv = rsqrtf(var + 1e-5f);
    int k = lane * 4;
    float o0 = (t.x - mu) * inv * b2f(g[k+0]) + b2f(b[k+0]);
    float o1 = (t.y - mu) * inv * b2f(g[k+1]) + b2f(b[k+1]);
    float o2 = (t.z - mu) * inv * b2f(g[k+2]) + b2f(b[k+2]);
    float o3 = (t.w - mu) * inv * b2f(g[k+3]) + b2f(b[k+3]);
    uint2 st = {pack2(o0, o1), pack2(o2, o3)};
    *reinterpret_cast<uint2*>(out + r * 256 + k) = st;
}

// ---------------- MFMA GEMM: out[M,J] = A @ WT^T + bias; cols split by blockIdx.y ----------------
// MODE 2: + raw residual ->f32; MODE 3: + f32 residual ->f32. 64 cols per block.
template <int K, int J, int MODE>
__global__ __launch_bounds__(256) void gemm_mfma(const bf16* __restrict__ A,
                                                 const bf16* __restrict__ WT,
                                                 const bf16* __restrict__ bias,
                                                 float* __restrict__ outf,
                                                 const void* __restrict__ resraw,
                                                 const float* __restrict__ resf,
                                                 const int* __restrict__ flags) {
    constexpr int LDK = K + 8;
    __shared__ bf16 As[32 * LDK];
    int tid = threadIdx.x;
    int row0 = blockIdx.x * 32;
    int col0 = blockIdx.y * 64;
    for (int t = tid; t < 32 * (K / 8); t += 256) {
        int r = t / (K / 8), kq = t % (K / 8);
        uint4 u = {0u, 0u, 0u, 0u};
        if (row0 + r < N_Q)
            u = *reinterpret_cast<const uint4*>(A + (size_t)(row0 + r) * K + kq * 8);
        *reinterpret_cast<uint4*>(&As[r * LDK + kq * 8]) = u;
    }
    __syncthreads();
    int wave = tid >> 6, lane = tid & 63;
    int l = lane & 15, quad = lane >> 4;
    int rh = wave >> 1, ch = wave & 1;
    constexpr int NK = K / 32;
    short8 afr[NK];
    const bf16* arow = &As[(rh * 16 + l) * LDK + quad * 8];
    #pragma unroll
    for (int ks = 0; ks < NK; ks++)
        afr[ks] = *reinterpret_cast<const short8*>(arow + ks * 32);
    int fdt = flags[0];
    #pragma unroll
    for (int ct = 0; ct < 2; ct++) {
        int col = col0 + ch * 32 + ct * 16 + l;
        const bf16* wrow = WT + (size_t)col * K + quad * 8;
        f32x4 acc = {0.f, 0.f, 0.f, 0.f};
        #pragma unroll
        for (int ks = 0; ks < NK; ks++) {
            short8 bfr = *reinterpret_cast<const short8*>(wrow + ks * 32);
            acc = mfma16(afr[ks], bfr, acc);
        }
        float bb = b2f(bias[col]);
        #pragma unroll
        for (int r = 0; r < 4; r++) {
            int row = row0 + rh * 16 + quad * 4 + r;
            if (row >= N_Q) continue;
            long o = (long)row * J + col;
            float v = acc[r] + bb;
            if (MODE == 2) outf[o] = v + load_any(resraw, o, fdt);
            else           outf[o] = v + resf[o];
        }
    }
}

// ---------------- Dual MFMA GEMM (concat cols J1|J2); out1=tanh*scale bf16, out2 plain bf16 ----
template <int K, int J1, int J2>
__global__ __launch_bounds__(256) void gemm_dual(const bf16* __restrict__ A,
                                                 const bf16* __restrict__ WT1,
                                                 const bf16* __restrict__ b1, float scale,
                                                 bf16* __restrict__ out1,
                                                 const bf16* __restrict__ WT2,
                                                 const bf16* __restrict__ b2,
                                                 bf16* __restrict__ out2) {
    constexpr int LDK = K + 8;
    __shared__ bf16 As[32 * LDK];
    int tid = threadIdx.x;
    int row0 = blockIdx.x * 32;
    int col0 = blockIdx.y * 64;
    for (int t = tid; t < 32 * (K / 8); t += 256) {
        int r = t / (K / 8), kq = t % (K / 8);
        uint4 u = {0u, 0u, 0u, 0u};
        if (row0 + r < N_Q)
            u = *reinterpret_cast<const uint4*>(A + (size_t)(row0 + r) * K + kq * 8);
        *reinterpret_cast<uint4*>(&As[r * LDK + kq * 8]) = u;
    }
    __syncthreads();
    int wave = tid >> 6, lane = tid & 63;
    int l = lane & 15, quad = lane >> 4;
    int rh = wave >> 1, ch = wave & 1;
    constexpr int NK = K / 32;
    short8 afr[NK];
    const bf16* arow = &As[(rh * 16 + l) * LDK + quad * 8];
    #pragma unroll
    for (int ks = 0; ks < NK; ks++)
        afr[ks] = *reinterpret_cast<const short8*>(arow + ks * 32);
    #pragma unroll
    for (int ct = 0; ct < 2; ct++) {
        int jg = col0 + ch * 32 + ct * 16 + l;
        int in1 = jg < J1;
        int cl = in1 ? jg : jg - J1;
        const bf16* wrow = (in1 ? WT1 : WT2) + (size_t)cl * K + quad * 8;
        f32x4 acc = {0.f, 0.f, 0.f, 0.f};
        #pragma unroll
        for (int ks = 0; ks < NK; ks++) {
            short8 bfr = *reinterpret_cast<const short8*>(wrow + ks * 32);
            acc = mfma16(afr[ks], bfr, acc);
        }
        float bb = b2f(in1 ? b1[cl] : b2[cl]);
        #pragma unroll
        for (int r = 0; r < 4; r++) {
            int row = row0 + rh * 16 + quad * 4 + r;
            if (row >= N_Q) continue;
            float v = acc[r] + bb;
            if (in1) out1[(long)row * J1 + cl] = f2b(tanhf(v) * scale);
            else     out2[(long)row * J2 + cl] = f2b(v);
        }
    }
}

// ---------------- Fused MFMA FFN: LN3 -> @w1T,relu -> @w2T -> +x -> out ----------------
__global__ __launch_bounds__(256) void ffn_mfma(const float* __restrict__ x,
                                                const bf16* __restrict__ g3,
                                                const bf16* __restrict__ b3,
                                                const bf16* __restrict__ w1T,
                                                const bf16* __restrict__ b1,
                                                const bf16* __restrict__ w2T,
                                                const bf16* __restrict__ b2v,
                                                void* __restrict__ out,
                                                const int* __restrict__ flags) {
    constexpr int LDH = DFF + 8;
    constexpr int LDX = D_MODEL + 8;
    __shared__ bf16 hbuf[16 * LDH];
    bf16* xl = hbuf;
    int tid = threadIdx.x;
    int row0 = blockIdx.x * 16;
    {
        int r = tid >> 4, lr = tid & 15;
        const float* xr = x + (long)(row0 + r) * 256 + lr * 16;
        float vals[16];
        float s1 = 0.f, s2 = 0.f;
        #pragma unroll
        for (int i = 0; i < 16; i++) {
            float v = xr[i];
            vals[i] = v; s1 += v; s2 += v * v;
        }
        #pragma unroll
        for (int off = 8; off > 0; off >>= 1) {
            s1 += __shfl_down(s1, off, 16);
            s2 += __shfl_down(s2, off, 16);
        }
        s1 = __shfl(s1, 0, 16);
        s2 = __shfl(s2, 0, 16);
        float mu = s1 * (1.f / 256.f);
        float var = s2 * (1.f / 256.f) - mu * mu;
        float inv = rsqrtf(var + 1e-5f);
        #pragma unroll
        for (int i = 0; i < 16; i++) {
            int k = lr * 16 + i;
            xl[r * LDX + k] = f2b((vals[i] - mu) * inv * b2f(g3[k]) + b2f(b3[k]));
        }
    }
    __syncthreads();
    int wave = tid >> 6, lane = tid & 63;
    int l = lane & 15, quad = lane >> 4;
    short8 afr[8];
    {
        const bf16* arow = xl + l * LDX + quad * 8;
        #pragma unroll
        for (int ks = 0; ks < 8; ks++)
            afr[ks] = *reinterpret_cast<const short8*>(arow + ks * 32);
    }
    __syncthreads();
    for (int ct = 0; ct < 16; ct++) {
        int col = wave * 256 + ct * 16 + l;
        const bf16* wrow = w1T + (size_t)col * 256 + quad * 8;
        f32x4 acc = {0.f, 0.f, 0.f, 0.f};
        #pragma unroll
        for (int ks = 0; ks < 8; ks++) {
            short8 bfr = *reinterpret_cast<const short8*>(wrow + ks * 32);
            acc = mfma16(afr[ks], bfr, acc);
        }
        float bb = b2f(b1[col]);
        #pragma unroll
        for (int r = 0; r < 4; r++)
            hbuf[(quad * 4 + r) * LDH + col] = f2b(fmaxf(acc[r] + bb, 0.f));
    }
    __syncthreads();
    int fdt = flags[0];
    for (int ct = 0; ct < 4; ct++) {
        int col = wave * 64 + ct * 16 + l;
        const bf16* wrow = w2T + (size_t)col * 1024 + quad * 8;
        const bf16* hrow = hbuf + l * LDH + quad * 8;
        f32x4 acc = {0.f, 0.f, 0.f, 0.f};
        #pragma unroll 8
        for (int ks = 0; ks < 32; ks++) {
            short8 a2 = *reinterpret_cast<const short8*>(hrow + ks * 32);
            short8 bfr = *reinterpret_cast<const short8*>(wrow + ks * 32);
            acc = mfma16(a2, bfr, acc);
        }
        float bb = b2f(b2v[col]);
        #pragma unroll
        for (int r = 0; r < 4; r++) {
            long o = (long)(row0 + quad * 4 + r) * 256 + col;
            store_any(out, o, fdt, x[o] + acc[r] + bb);
        }
    }
}

// ---------------- Temporal sampling (8 q/block, 8 ch/thread, branchless corners) ----------------
__global__ __launch_bounds__(256) void temporal_kernel(const bf16* __restrict__ ai,
                                                       const bf16* __restrict__ toffB,
                                                       const bf16* __restrict__ twlB,
                                                       const void* __restrict__ ref2d,
                                                       const void* __restrict__ ego,
                                                       const int* __restrict__ flags,
                                                       bf16* __restrict__ tfB) {
    int tid = threadIdx.x;
    int ql = tid >> 5, t = tid & 31;
    int g = t >> 2, q4 = t & 3;
    long n0 = (long)blockIdx.x * 8;
    __shared__ float s_toff[8][8][17];
    __shared__ float s_twl[8][64];
    __shared__ float s_base[8][4];
    for (int i = tid; i < 8 * 128; i += 256) {
        int q = i >> 7, j = i & 127;
        int si = j >> 6, r = j & 63, gg = r >> 3, w = r & 7;
        s_toff[q][gg][si * 8 + w] = b2f(toffB[n0 * 128 + i]);
    }
    for (int i = tid; i < 8 * 64; i += 256) s_twl[i >> 6][i & 63] = b2f(twlB[n0 * 64 + i]);
    if (tid < 8) {
        int f = flags[0];
        float rx = load_any(ref2d, (n0 + tid) * 2, f), ry = load_any(ref2d, (n0 + tid) * 2 + 1, f);
        s_base[tid][0] = rx + load_any(ego, 0, f); s_base[tid][1] = ry + load_any(ego, 1, f);
        s_base[tid][2] = rx;                       s_base[tid][3] = ry;
    }
    __syncthreads();
    float acc[8];
    #pragma unroll
    for (int i = 0; i < 8; i++) acc[i] = 0.f;
    int choff = g * 32 + q4 * 8;
    #pragma unroll
    for (int si = 0; si < 2; si++) {
        float l0 = s_twl[ql][si * 32 + g * 4 + 0], l1 = s_twl[ql][si * 32 + g * 4 + 1];
        float l2 = s_twl[ql][si * 32 + g * 4 + 2], l3 = s_twl[ql][si * 32 + g * 4 + 3];
        float mx = fmaxf(fmaxf(l0, l1), fmaxf(l2, l3));
        float e0 = __expf(l0 - mx), e1 = __expf(l1 - mx);
        float e2 = __expf(l2 - mx), e3 = __expf(l3 - mx);
        float inv = 1.f / (e0 + e1 + e2 + e3);
        float wts[4] = {e0 * inv, e1 * inv, e2 * inv, e3 * inv};
        int aoff = si * 256;
        float bx = s_base[ql][si * 2], by = s_base[ql][si * 2 + 1];
        #pragma unroll
        for (int pt = 0; pt < 4; pt++) {
            float u = bx + s_toff[ql][g][si * 8 + pt * 2 + 0];
            float v = by + s_toff[ql][g][si * 8 + pt * 2 + 1];
            float ix = u * (float)BW - 0.5f;
            float iy = v * (float)BH - 0.5f;
            float x0f = floorf(ix), y0f = floorf(iy);
            int x0 = (int)x0f, y0 = (int)y0f;
            float wx1 = ix - x0f, wy1 = iy - y0f;
            float wxv[2] = {(1.f - wx1) * ((unsigned)x0 < BW ? 1.f : 0.f),
                            wx1 * ((unsigned)(x0 + 1) < BW ? 1.f : 0.f)};
            float wyv[2] = {(1.f - wy1) * ((unsigned)y0 < BH ? 1.f : 0.f),
                            wy1 * ((unsigned)(y0 + 1) < BH ? 1.f : 0.f)};
            int xc[2] = {min(max(x0, 0), BW - 1), min(max(x0 + 1, 0), BW - 1)};
            int yc[2] = {min(max(y0, 0), BH - 1), min(max(y0 + 1, 0), BH - 1)};
            #pragma unroll
            for (int cy = 0; cy < 2; cy++) {
                #pragma unroll
                for (int cx = 0; cx < 2; cx++) {
                    float wq = wts[pt] * wyv[cy] * wxv[cx];
                    uint4 uu = *reinterpret_cast<const uint4*>(
                        ai + (long)(yc[cy] * BW + xc[cx]) * 512 + aoff + choff);
                    acc[0] += wq * __uint_as_float(uu.x << 16);
                    acc[1] += wq * __uint_as_float(uu.x & 0xFFFF0000u);
                    acc[2] += wq * __uint_as_float(uu.y << 16);
                    acc[3] += wq * __uint_as_float(uu.y & 0xFFFF0000u);
                    acc[4] += wq * __uint_as_float(uu.z << 16);
                    acc[5] += wq * __uint_as_float(uu.z & 0xFFFF0000u);
                    acc[6] += wq * __uint_as_float(uu.w << 16);
                    acc[7] += wq * __uint_as_float(uu.w & 0xFFFF0000u);
                }
            }
        }
    }
    uint4 o;
    o.x = pack2(acc[0] * 0.5f, acc[1] * 0.5f);
    o.y = pack2(acc[2] * 0.5f, acc[3] * 0.5f);
    o.z = pack2(acc[4] * 0.5f, acc[5] * 0.5f);
    o.w = pack2(acc[6] * 0.5f, acc[7] * 0.5f);
    *reinterpret_cast<uint4*>(tfB + (n0 + ql) * 256 + choff) = o;
}

// ---------------- Spatial sampling v4: conflict-free swl layout + branchless corners ----------------
__global__ __launch_bounds__(128) void spatial_kernel(const bf16* __restrict__ soffB,
                                                      const bf16* __restrict__ swlB,
                                                      const void* __restrict__ refcam,
                                                      const void* __restrict__ bmask,
                                                      const bf16* __restrict__ imgT,
                                                      const void* __restrict__ img_raw,
                                                      int use_imgT,
                                                      const int* __restrict__ flags,
                                                      bf16* __restrict__ sfB) {
    int tid = threadIdx.x;
    int ql = tid >> 5, t = tid & 31;
    int g = t >> 2, q4 = t & 3;
    long n0 = (long)blockIdx.x * 4;
    __shared__ float s_soff[4][8][33];
    __shared__ float s_swl[4][144];        // [q][j*9 + g] — 16-bank spread, broadcast-free
    __shared__ float s_ref[4][NC][PP][2];
    __shared__ int   s_vis[4][NC][PP];
    for (int i = tid; i < 4 * 256; i += 128) {
        int q = i >> 8, j = i & 255;
        s_soff[q][j >> 5][j & 31] = b2f(soffB[n0 * 256 + i]);
    }
    for (int i = tid; i < 4 * 128; i += 128) {
        int q = i >> 7, jr = i & 127;
        int gg = jr >> 4, j = jr & 15;
        s_swl[q][j * 9 + gg] = b2f(swlB[n0 * 128 + i]);
    }
    int fdt = flags[0], msz = flags[1];
    for (int i = tid; i < 4 * 48; i += 128) {
        int q = i / 48, r = i % 48;
        s_ref[q][r >> 3][(r & 7) >> 1][r & 1] =
            load_any(refcam, ((long)(r >> 3) * N_Q + n0 + q) * 8 + (r & 7), fdt);
    }
    if (tid < 4 * 24) {
        int q = tid / 24, r = tid % 24; int c = r >> 2, p = r & 3;
        long idx = ((long)c * N_Q + n0 + q) * 4 + p;
        int v;
        if (msz == 1)      v = ((const unsigned char*)bmask)[idx] != 0;
        else if (msz == 2) v = ((const unsigned short*)bmask)[idx] != 0;
        else if (msz == 4) v = ((const unsigned int*)bmask)[idx] != 0u;
        else               v = ((const unsigned long long*)bmask)[idx] != 0ULL;
        s_vis[q][c][p] = v;
    }
    __syncthreads();
    float acc[8];
    #pragma unroll
    for (int i = 0; i < 8; i++) acc[i] = 0.f;
    float cnt = 0.f;
    int choff = g * 32 + q4 * 8;
    for (int c = 0; c < NC; c++) {
        if (!(s_vis[ql][c][0] | s_vis[ql][c][1] | s_vis[ql][c][2] | s_vis[ql][c][3])) continue;
        cnt += 1.f;
        float w[16], mx = -3e38f;
        #pragma unroll
        for (int j = 0; j < 16; j++) {
            float li = s_vis[ql][c][j >> 2] ? s_swl[ql][j * 9 + g] : -3e38f;
            w[j] = li; mx = fmaxf(mx, li);
        }
        float sum = 0.f;
        #pragma unroll
        for (int j = 0; j < 16; j++) {
            float e = (w[j] > -1e37f) ? __expf(w[j] - mx) : 0.f;
            w[j] = e; sum += e;
        }
        float inv = 1.f / fmaxf(sum, 1e-20f);
        const bf16* img = imgT + (long)c * HF * WF * 256 + choff;
        #pragma unroll
        for (int p = 0; p < PP; p++) {
            if (!s_vis[ql][c][p]) continue;
            float rx = s_ref[ql][c][p][0], ry = s_ref[ql][c][p][1];
            #pragma unroll
            for (int s = 0; s < PS; s++) {
                float wi = w[p * 4 + s] * inv;
                float u = rx + s_soff[ql][g][p * 8 + s * 2 + 0];
                float v = ry + s_soff[ql][g][p * 8 + s * 2 + 1];
                float ix = u * (float)WF - 0.5f, iy = v * (float)HF - 0.5f;
                float x0f = floorf(ix), y0f = floorf(iy);
                int x0 = (int)x0f, y0 = (int)y0f;
                float wx1 = ix - x0f, wy1 = iy - y0f;
                float wxv[2] = {(1.f - wx1) * ((unsigned)x0 < WF ? 1.f : 0.f),
                                wx1 * ((unsigned)(x0 + 1) < WF ? 1.f : 0.f)};
                float wyv[2] = {(1.f - wy1) * ((unsigned)y0 < HF ? 1.f : 0.f),
                                wy1 * ((unsigned)(y0 + 1) < HF ? 1.f : 0.f)};
                int xc[2] = {min(max(x0, 0), WF - 1), min(max(x0 + 1, 0), WF - 1)};
                int yc[2] = {min(max(y0, 0), HF - 1), min(max(y0 + 1, 0), HF - 1)};
                #pragma unroll
                for (int cy = 0; cy < 2; cy++) {
                    #pragma unroll
                    for (int cx = 0; cx < 2; cx++) {
                        float wq = wi * wyv[cy] * wxv[cx];
                        if (use_imgT) {
                            uint4 uu = *reinterpret_cast<const uint4*>(
                                img + (long)(yc[cy] * WF + xc[cx]) * 256);
                            acc[0] += wq * __uint_as_float(uu.x << 16);
                            acc[1] += wq * __uint_as_float(uu.x & 0xFFFF0000u);
                            acc[2] += wq * __uint_as_float(uu.y << 16);
                            acc[3] += wq * __uint_as_float(uu.y & 0xFFFF0000u);
                            acc[4] += wq * __uint_as_float(uu.z << 16);
                            acc[5] += wq * __uint_as_float(uu.z & 0xFFFF0000u);
                            acc[6] += wq * __uint_as_float(uu.w << 16);
                            acc[7] += wq * __uint_as_float(uu.w & 0xFFFF0000u);
                        } else {
                            #pragma unroll
                            for (int e = 0; e < 8; e++)
                                acc[e] += wq * load_any(img_raw,
                                    (((long)c * 256 + choff + e) * HF + yc[cy]) * WF + xc[cx], fdt);
                        }
                    }
                }
            }
        }
    }
    float invc = 1.f / fmaxf(cnt, 1.f);
    uint4 o;
    o.x = pack2(acc[0] * invc, acc[1] * invc);
    o.y = pack2(acc[2] * invc, acc[3] * invc);
    o.z = pack2(acc[4] * invc, acc[5] * invc);
    o.w = pack2(acc[6] * invc, acc[7] * invc);
    *reinterpret_cast<uint4*>(sfB + (n0 + ql) * 256 + choff) = o;
}

// bf16 element offsets inside the weight region (matrices stored TRANSPOSED [J][K])
#define W_TOFF_W 0
#define W_TOFF_B 65536
#define W_TWT_W  65664
#define W_TWT_B  98432
#define W_TOUT_W 98496
#define W_TOUT_B 164032
#define W_SOFF_W 164288
#define W_SOFF_B 229824
#define W_SWT_W  230080
#define W_SWT_B  262848
#define W_SOUT_W 262976
#define W_SOUT_B 328512
#define W_FFN_W1 328768
#define W_FFN_B1 590912
#define W_FFN_W2 591936
#define W_FFN_B2 854080
#define W_LN1_G  854336
#define W_LN1_B  854592
#define W_LN2_G  854848
#define W_LN2_B  855104
#define W_LN3_G  855360
#define W_LN3_B  855616

// byte offsets in workspace (total ~35.6 MB)
#define OB_WGT   0
#define OB_FLAGS 1711744
#define OB_AI    1712640
#define OB_TF    11952640
#define OB_X     17072640
#define OB_T4    27312640
#define OB_IMG   31152640
#define WS_NEED_IMG 35576320ULL

extern "C" void kernel_launch(void* const* d_in, const int* in_sizes, int n_in,
                              void* d_out, int out_size, void* d_ws, size_t ws_size,
                              hipStream_t stream) {
    char* W8 = (char*)d_ws;
    bf16*  wgt   = (bf16*)(W8 + OB_WGT);
    int*   flags = (int*)(W8 + OB_FLAGS);
    bf16*  ai    = (bf16*)(W8 + OB_AI);                 // N x 512, pb | q1
    bf16*  q2B   = ai;                                  // N x 256 (after temporal)
    bf16*  sfB   = (bf16*)(W8 + OB_AI + 5120000);       // N x 256
    bf16*  tfB   = (bf16*)(W8 + OB_TF);                 // N x 256
    bf16*  soffB = tfB;                                 // N x 256 (after t_out gemm)
    float* x     = (float*)(W8 + OB_X);                 // N x 256 f32 trunk
    bf16*  toffB = (bf16*)(W8 + OB_T4);                 // N x 128
    bf16*  twlB  = (bf16*)(W8 + OB_T4 + 2560000);       // N x 64
    bf16*  swlB  = toffB;                               // N x 128 (after temporal)
    bf16*  imgT  = (bf16*)(W8 + OB_IMG);                // NC*HF*WF*256
    int use_imgT = (ws_size >= WS_NEED_IMG) ? 1 : 0;

    detect_kernel<<<1, 256, 0, stream>>>(d_in[22], d_in[28], flags);

    {   // unified prep: 8 transposes + 14 flat cvts + img transpose
        PrepDesc pd;
        const int tsrc[8] = {6, 8, 10, 12, 14, 16, 18, 20};
        const int toff[8] = {W_TOFF_W, W_TWT_W, W_TOUT_W, W_SOFF_W, W_SWT_W, W_SOUT_W,
                             W_FFN_W1, W_FFN_W2};
        const int tR[8] = {512, 512, 256, 256, 256, 256, 256, 1024};
        const int tC[8] = {128, 64, 256, 256, 128, 256, 1024, 256};
        const int fsrc[14] = {7, 9, 11, 13, 15, 17, 19, 21, 22, 23, 24, 25, 26, 27};
        const int foff[14] = {W_TOFF_B, W_TWT_B, W_TOUT_B, W_SOFF_B, W_SWT_B, W_SOUT_B,
                              W_FFN_B1, W_FFN_B2, W_LN1_G, W_LN1_B, W_LN2_G, W_LN2_B,
                              W_LN3_G, W_LN3_B};
        const int fcnt[14] = {128, 64, 256, 256, 128, 256, 1024, 256, 256, 256, 256, 256, 256, 256};
        int a = 0, blk = 0;
        for (int i = 0; i < 8; i++, a++) {
            pd.src[a] = d_in[tsrc[i]]; pd.dst_off[a] = toff[i];
            pd.count[a] = tR[i] * tC[i]; pd.R[a] = tR[i]; pd.C[a] = tC[i];
            pd.type[a] = 1; pd.blk_start[a] = blk; blk += (pd.count[a] + 255) / 256;
        }
        for (int i = 0; i < 14; i++, a++) {
            pd.src[a] = d_in[fsrc[i]]; pd.dst_off[a] = foff[i];
            pd.count[a] = fcnt[i]; pd.R[a] = 0; pd.C[a] = 0;
            pd.type[a] = 0; pd.blk_start[a] = blk; blk += (pd.count[a] + 255) / 256;
        }
        pd.src[a] = d_in[2]; pd.dst_off[a] = 0;
        pd.count[a] = use_imgT ? NC * HF * WF * 256 : 0;
        pd.R[a] = 0; pd.C[a] = 0; pd.type[a] = 2; pd.blk_start[a] = blk;
        blk += (pd.count[a] + 255) / 256;
        pd.blk_start[NP] = blk;
        prep_kernel<<<blk, 256, 0, stream>>>(pd, wgt, imgT, flags);
    }

    ln12_kernel<<<5000, 256, 0, stream>>>(d_in[1], d_in[0], flags,
                                          wgt + W_LN1_G, wgt + W_LN1_B, ai);
    gemm_dual<512, 128, 64><<<dim3(313, 3), 256, 0, stream>>>(ai,
        wgt + W_TOFF_W, wgt + W_TOFF_B, T_RAD, toffB,
        wgt + W_TWT_W, wgt + W_TWT_B, twlB);
    temporal_kernel<<<1250, 256, 0, stream>>>(ai, toffB, twlB, d_in[3], d_in[5], flags, tfB);
    gemm_mfma<256, 256, 2><<<dim3(313, 4), 256, 0, stream>>>(tfB, wgt + W_TOUT_W, wgt + W_TOUT_B,
        x, d_in[0], nullptr, flags);
    ln_kernel<<<2500, 256, 0, stream>>>(x, wgt + W_LN2_G, wgt + W_LN2_B, q2B);
    gemm_dual<256, 256, 128><<<dim3(313, 6), 256, 0, stream>>>(q2B,
        wgt + W_SOFF_W, wgt + W_SOFF_B, S_RAD, soffB,
        wgt + W_SWT_W, wgt + W_SWT_B, swlB);
    spatial_kernel<<<2500, 128, 0, stream>>>(soffB, swlB, d_in[4], d_in[28], imgT, d_in[2],
                                             use_imgT, flags, sfB);
    gemm_mfma<256, 256, 3><<<dim3(313, 4), 256, 0, stream>>>(sfB, wgt + W_SOUT_W, wgt + W_SOUT_B,
        x, nullptr, x, flags);
    ffn_mfma<<<625, 256, 0, stream>>>(x, wgt + W_LN3_G, wgt + W_LN3_B,
                                      wgt + W_FFN_W1, wgt + W_FFN_B1,
                                      wgt + W_FFN_W2, wgt + W_FFN_B2, d_out, flags);
}

// Round 8
// 497.822 us; speedup vs baseline: 2.5680x; 1.1401x over previous
//
#include <hip/hip_runtime.h>
#include <hip/hip_bf16.h>
#include <hip/hip_fp16.h>

#define N_Q 10000
#define D_MODEL 256
#define NH 8
#define PT 4
#define PP 4
#define PS 4
#define DFF 1024
#define NC 6
#define HF 24
#define WF 60
#define BH 100
#define BW 100
#define T_RAD 0.15f
#define S_RAD 0.12f

typedef __hip_bfloat16 bf16;
typedef __attribute__((ext_vector_type(8))) short short8;
typedef __attribute__((ext_vector_type(4))) float f32x4;

__device__ __forceinline__ float b2f(bf16 v) { return __bfloat162float(v); }
__device__ __forceinline__ bf16 f2b(float v) { return __float2bfloat16(v); }

__device__ __forceinline__ f32x4 mfma16(short8 a, short8 b, f32x4 c) {
    return __builtin_amdgcn_mfma_f32_16x16x32_bf16(a, b, c, 0, 0, 0);
}

// dtype-adaptive loads/stores; f: 0=f32, 1=bf16, 2=f16
__device__ __forceinline__ float load_any(const void* p, long i, int f) {
    if (f == 0) return ((const float*)p)[i];
    if (f == 1) return b2f(((const bf16*)p)[i]);
    return __half2float(((const __half*)p)[i]);
}
__device__ __forceinline__ void store_any(void* p, long i, int f, float v) {
    if (f == 0)      ((float*)p)[i] = v;
    else if (f == 1) ((bf16*)p)[i] = f2b(v);
    else             ((__half*)p)[i] = __float2half(v);
}

__device__ __forceinline__ unsigned pack2(float a, float b) {
    bf16 x = f2b(a), y = f2b(b);
    unsigned short ux = *(unsigned short*)&x, uy = *(unsigned short*)&y;
    return (unsigned)ux | ((unsigned)uy << 16);
}

// ---------------- dtype / mask-width detection (parallel) ----------------
__global__ __launch_bounds__(256) void detect_kernel(const void* __restrict__ ln1g,
                                                     const void* __restrict__ mask,
                                                     int* __restrict__ flags) {
    __shared__ int sh[6];
    int tid = threadIdx.x;
    if (tid < 6) sh[tid] = (tid == 0 || tid == 2 || tid == 4) ? 1 : 0;
    __syncthreads();
    const unsigned long long* m64 = (const unsigned long long*)mask;
    const unsigned int*       m32 = (const unsigned int*)mask;
    const unsigned short*     m16 = (const unsigned short*)mask;
    int lok8 = 1, lones8 = 0, lok4 = 1, lones4 = 0, lok2 = 1, lones2 = 0;
    for (int i = tid; i < 480; i += 256) {
        if (i < 120) {
            unsigned long long v = m64[i];
            if (v == 1ULL) lones8++; else if (v != 0ULL) lok8 = 0;
        }
        if (i < 240) {
            unsigned int v = m32[i];
            if (v == 1u || v == 0x3F800000u) lones4++; else if (v != 0u) lok4 = 0;
        }
        unsigned short v = m16[i];
        if (v == 1 || v == 0x3F80) lones2++; else if (v != 0) lok2 = 0;
    }
    atomicAnd(&sh[0], lok8); atomicAdd(&sh[1], lones8);
    atomicAnd(&sh[2], lok4); atomicAdd(&sh[3], lones4);
    atomicAnd(&sh[4], lok2); atomicAdd(&sh[5], lones2);
    __syncthreads();
    if (tid == 0) {
        unsigned short u0 = ((const unsigned short*)ln1g)[0];
        flags[0] = (u0 == 0x3F80) ? 1 : (u0 == 0x3C00 ? 2 : 0);
        int ms;
        if (sh[0] && sh[1] > 30)       ms = 8;
        else if (sh[2] && sh[3] > 60)  ms = 4;
        else if (sh[4] && sh[5] > 120) ms = 2;
        else                           ms = 1;
        flags[1] = ms;
    }
}

// ---------------- unified weight/image prep: transposes + flat cvt + img transpose ----------------
#define NP 23
struct PrepDesc {
    const void* src[NP];
    int dst_off[NP];
    int count[NP];
    int R[NP];
    int C[NP];
    int type[NP];       // 0 flat cvt, 1 transpose, 2 img transpose
    int blk_start[NP + 1];
};
__global__ __launch_bounds__(256) void prep_kernel(PrepDesc pd, bf16* __restrict__ wgt,
                                                   bf16* __restrict__ imgT,
                                                   const int* __restrict__ flags) {
    int blk = blockIdx.x;
    int a = 0;
    while (a < NP - 1 && blk >= pd.blk_start[a + 1]) a++;
    int i = (blk - pd.blk_start[a]) * 256 + threadIdx.x;
    if (i >= pd.count[a]) return;
    int f = flags[0];
    int ty = pd.type[a];
    if (ty == 0) {
        wgt[pd.dst_off[a] + i] = f2b(load_any(pd.src[a], i, f));
    } else if (ty == 1) {
        int R = pd.R[a], C = pd.C[a];
        int c = i / R, r = i % R;
        wgt[pd.dst_off[a] + i] = f2b(load_any(pd.src[a], (long)r * C + c, f));
    } else {
        int ch = i & 255;
        int t = i >> 8;
        int xx = t % WF; t /= WF;
        int yy = t % HF;
        int c  = t / HF;
        long src = (((long)(c * 256) + ch) * HF + yy) * WF + xx;
        imgT[i] = f2b(load_any(pd.src[a], src, f));
    }
}

// ---------------- LN1 over prev_bev & query, wave-per-row -> ai[N,512] ----------------
__global__ __launch_bounds__(256) void ln12_kernel(const void* __restrict__ pb,
                                                   const void* __restrict__ q,
                                                   const int* __restrict__ flags,
                                                   const bf16* __restrict__ g,
                                                   const bf16* __restrict__ b,
                                                   bf16* __restrict__ out) {
    int wv = threadIdx.x >> 6, lane = threadIdx.x & 63;
    long row = (long)blockIdx.x * 4 + wv;
    const void* src; long r; int ooff;
    if (row < N_Q) { src = pb; r = row; ooff = 0; }
    else           { src = q;  r = row - N_Q; ooff = 256; }
    int f = flags[0];
    float v0, v1, v2, v3;
    if (f == 0) {
        float4 t = ((const float4*)src)[r * 64 + lane];
        v0 = t.x; v1 = t.y; v2 = t.z; v3 = t.w;
    } else {
        uint2 t = ((const uint2*)src)[r * 64 + lane];
        if (f == 1) {
            v0 = __uint_as_float(t.x << 16); v1 = __uint_as_float(t.x & 0xFFFF0000u);
            v2 = __uint_as_float(t.y << 16); v3 = __uint_as_float(t.y & 0xFFFF0000u);
        } else {
            __half2 h0 = *(__half2*)&t.x, h1 = *(__half2*)&t.y;
            v0 = __half2float(h0.x); v1 = __half2float(h0.y);
            v2 = __half2float(h1.x); v3 = __half2float(h1.y);
        }
    }
    float s1 = v0 + v1 + v2 + v3;
    float s2 = v0 * v0 + v1 * v1 + v2 * v2 + v3 * v3;
    #pragma unroll
    for (int m = 32; m > 0; m >>= 1) {
        s1 += __shfl_xor(s1, m);
        s2 += __shfl_xor(s2, m);
    }
    float mu = s1 * (1.f / 256.f);
    float var = s2 * (1.f / 256.f) - mu * mu;
    float inv = rsqrtf(var + 1e-5f);
    int k = lane * 4;
    float o0 = (v0 - mu) * inv * b2f(g[k+0]) + b2f(b[k+0]);
    float o1 = (v1 - mu) * inv * b2f(g[k+1]) + b2f(b[k+1]);
    float o2 = (v2 - mu) * inv * b2f(g[k+2]) + b2f(b[k+2]);
    float o3 = (v3 - mu) * inv * b2f(g[k+3]) + b2f(b[k+3]);
    uint2 st = {pack2(o0, o1), pack2(o2, o3)};
    *reinterpret_cast<uint2*>(out + r * 512 + ooff + k) = st;
}

// ---------------- LayerNorm (f32 in), wave-per-row -> bf16 out ----------------
__global__ __launch_bounds__(256) void ln_kernel(const float* __restrict__ in,
                                                 const bf16* __restrict__ g,
                                                 const bf16* __restrict__ b,
                                                 bf16* __restrict__ out) {
    int wv = threadIdx.x >> 6, lane = threadIdx.x & 63;
    long r = (long)blockIdx.x * 4 + wv;
    float4 t = ((const float4*)in)[r * 64 + lane];
    float s1 = t.x + t.y + t.z + t.w;
    float s2 = t.x * t.x + t.y * t.y + t.z * t.z + t.w * t.w;
    #pragma unroll
    for (int m = 32; m > 0; m >>= 1) {
        s1 += __shfl_xor(s1, m);
        s2 += __shfl_xor(s2, m);
    }
    float mu = s1 * (1.f / 256.f);
    float var = s2 * (1.f / 256.f) - mu * mu;
    float inv = rsqrtf(var + 1e-5f);
    int k = lane * 4;
    float o0 = (t.x - mu) * inv * b2f(g[k+0]) + b2f(b[k+0]);
    float o1 = (t.y - mu) * inv * b2f(g[k+1]) + b2f(b[k+1]);
    float o2 = (t.z - mu) * inv * b2f(g[k+2]) + b2f(b[k+2]);
    float o3 = (t.w - mu) * inv * b2f(g[k+3]) + b2f(b[k+3]);
    uint2 st = {pack2(o0, o1), pack2(o2, o3)};
    *reinterpret_cast<uint2*>(out + r * 256 + k) = st;
}

// ---------------- MFMA GEMM: out[M,J] = A @ WT^T + bias; cols split by blockIdx.y ----------------
template <int K, int J, int MODE>
__global__ __launch_bounds__(256) void gemm_mfma(const bf16* __restrict__ A,
                                                 const bf16* __restrict__ WT,
                                                 const bf16* __restrict__ bias,
                                                 float* __restrict__ outf,
                                                 const void* __restrict__ resraw,
                                                 const float* __restrict__ resf,
                                                 const int* __restrict__ flags) {
    constexpr int LDK = K + 8;
    __shared__ bf16 As[32 * LDK];
    int tid = threadIdx.x;
    int row0 = blockIdx.x * 32;
    int col0 = blockIdx.y * 64;
    for (int t = tid; t < 32 * (K / 8); t += 256) {
        int r = t / (K / 8), kq = t % (K / 8);
        uint4 u = {0u, 0u, 0u, 0u};
        if (row0 + r < N_Q)
            u = *reinterpret_cast<const uint4*>(A + (size_t)(row0 + r) * K + kq * 8);
        *reinterpret_cast<uint4*>(&As[r * LDK + kq * 8]) = u;
    }
    __syncthreads();
    int wave = tid >> 6, lane = tid & 63;
    int l = lane & 15, quad = lane >> 4;
    int rh = wave >> 1, ch = wave & 1;
    constexpr int NK = K / 32;
    short8 afr[NK];
    const bf16* arow = &As[(rh * 16 + l) * LDK + quad * 8];
    #pragma unroll
    for (int ks = 0; ks < NK; ks++)
        afr[ks] = *reinterpret_cast<const short8*>(arow + ks * 32);
    int fdt = flags[0];
    #pragma unroll
    for (int ct = 0; ct < 2; ct++) {
        int col = col0 + ch * 32 + ct * 16 + l;
        const bf16* wrow = WT + (size_t)col * K + quad * 8;
        f32x4 acc = {0.f, 0.f, 0.f, 0.f};
        #pragma unroll
        for (int ks = 0; ks < NK; ks++) {
            short8 bfr = *reinterpret_cast<const short8*>(wrow + ks * 32);
            acc = mfma16(afr[ks], bfr, acc);
        }
        float bb = b2f(bias[col]);
        #pragma unroll
        for (int r = 0; r < 4; r++) {
            int row = row0 + rh * 16 + quad * 4 + r;
            if (row >= N_Q) continue;
            long o = (long)row * J + col;
            float v = acc[r] + bb;
            if (MODE == 2) outf[o] = v + load_any(resraw, o, fdt);
            else           outf[o] = v + resf[o];
        }
    }
}

// ---------------- Dual MFMA GEMM (concat cols J1|J2); out1=tanh*scale bf16, out2 plain bf16 ----
template <int K, int J1, int J2>
__global__ __launch_bounds__(256) void gemm_dual(const bf16* __restrict__ A,
                                                 const bf16* __restrict__ WT1,
                                                 const bf16* __restrict__ b1, float scale,
                                                 bf16* __restrict__ out1,
                                                 const bf16* __restrict__ WT2,
                                                 const bf16* __restrict__ b2,
                                                 bf16* __restrict__ out2) {
    constexpr int LDK = K + 8;
    __shared__ bf16 As[32 * LDK];
    int tid = threadIdx.x;
    int row0 = blockIdx.x * 32;
    int col0 = blockIdx.y * 64;
    for (int t = tid; t < 32 * (K / 8); t += 256) {
        int r = t / (K / 8), kq = t % (K / 8);
        uint4 u = {0u, 0u, 0u, 0u};
        if (row0 + r < N_Q)
            u = *reinterpret_cast<const uint4*>(A + (size_t)(row0 + r) * K + kq * 8);
        *reinterpret_cast<uint4*>(&As[r * LDK + kq * 8]) = u;
    }
    __syncthreads();
    int wave = tid >> 6, lane = tid & 63;
    int l = lane & 15, quad = lane >> 4;
    int rh = wave >> 1, ch = wave & 1;
    constexpr int NK = K / 32;
    short8 afr[NK];
    const bf16* arow = &As[(rh * 16 + l) * LDK + quad * 8];
    #pragma unroll
    for (int ks = 0; ks < NK; ks++)
        afr[ks] = *reinterpret_cast<const short8*>(arow + ks * 32);
    #pragma unroll
    for (int ct = 0; ct < 2; ct++) {
        int jg = col0 + ch * 32 + ct * 16 + l;
        int in1 = jg < J1;
        int cl = in1 ? jg : jg - J1;
        const bf16* wrow = (in1 ? WT1 : WT2) + (size_t)cl * K + quad * 8;
        f32x4 acc = {0.f, 0.f, 0.f, 0.f};
        #pragma unroll
        for (int ks = 0; ks < NK; ks++) {
            short8 bfr = *reinterpret_cast<const short8*>(wrow + ks * 32);
            acc = mfma16(afr[ks], bfr, acc);
        }
        float bb = b2f(in1 ? b1[cl] : b2[cl]);
        #pragma unroll
        for (int r = 0; r < 4; r++) {
            int row = row0 + rh * 16 + quad * 4 + r;
            if (row >= N_Q) continue;
            float v = acc[r] + bb;
            if (in1) out1[(long)row * J1 + cl] = f2b(tanhf(v) * scale);
            else     out2[(long)row * J2 + cl] = f2b(v);
        }
    }
}

// ---------------- Fused MFMA FFN: LN3 -> @w1T,relu -> @w2T -> +x -> out ----------------
__global__ __launch_bounds__(256) void ffn_mfma(const float* __restrict__ x,
                                                const bf16* __restrict__ g3,
                                                const bf16* __restrict__ b3,
                                                const bf16* __restrict__ w1T,
                                                const bf16* __restrict__ b1,
                                                const bf16* __restrict__ w2T,
                                                const bf16* __restrict__ b2v,
                                                void* __restrict__ out,
                                                const int* __restrict__ flags) {
    constexpr int LDH = DFF + 8;
    constexpr int LDX = D_MODEL + 8;
    __shared__ bf16 hbuf[16 * LDH];
    bf16* xl = hbuf;
    int tid = threadIdx.x;
    int row0 = blockIdx.x * 16;
    {
        int r = tid >> 4, lr = tid & 15;
        const float* xr = x + (long)(row0 + r) * 256 + lr * 16;
        float vals[16];
        float s1 = 0.f, s2 = 0.f;
        #pragma unroll
        for (int i = 0; i < 16; i++) {
            float v = xr[i];
            vals[i] = v; s1 += v; s2 += v * v;
        }
        #pragma unroll
        for (int off = 8; off > 0; off >>= 1) {
            s1 += __shfl_down(s1, off, 16);
            s2 += __shfl_down(s2, off, 16);
        }
        s1 = __shfl(s1, 0, 16);
        s2 = __shfl(s2, 0, 16);
        float mu = s1 * (1.f / 256.f);
        float var = s2 * (1.f / 256.f) - mu * mu;
        float inv = rsqrtf(var + 1e-5f);
        #pragma unroll
        for (int i = 0; i < 16; i++) {
            int k = lr * 16 + i;
            xl[r * LDX + k] = f2b((vals[i] - mu) * inv * b2f(g3[k]) + b2f(b3[k]));
        }
    }
    __syncthreads();
    int wave = tid >> 6, lane = tid & 63;
    int l = lane & 15, quad = lane >> 4;
    short8 afr[8];
    {
        const bf16* arow = xl + l * LDX + quad * 8;
        #pragma unroll
        for (int ks = 0; ks < 8; ks++)
            afr[ks] = *reinterpret_cast<const short8*>(arow + ks * 32);
    }
    __syncthreads();
    for (int ct = 0; ct < 16; ct++) {
        int col = wave * 256 + ct * 16 + l;
        const bf16* wrow = w1T + (size_t)col * 256 + quad * 8;
        f32x4 acc = {0.f, 0.f, 0.f, 0.f};
        #pragma unroll
        for (int ks = 0; ks < 8; ks++) {
            short8 bfr = *reinterpret_cast<const short8*>(wrow + ks * 32);
            acc = mfma16(afr[ks], bfr, acc);
        }
        float bb = b2f(b1[col]);
        #pragma unroll
        for (int r = 0; r < 4; r++)
            hbuf[(quad * 4 + r) * LDH + col] = f2b(fmaxf(acc[r] + bb, 0.f));
    }
    __syncthreads();
    int fdt = flags[0];
    for (int ct = 0; ct < 4; ct++) {
        int col = wave * 64 + ct * 16 + l;
        const bf16* wrow = w2T + (size_t)col * 1024 + quad * 8;
        const bf16* hrow = hbuf + l * LDH + quad * 8;
        f32x4 acc = {0.f, 0.f, 0.f, 0.f};
        #pragma unroll 8
        for (int ks = 0; ks < 32; ks++) {
            short8 a2 = *reinterpret_cast<const short8*>(hrow + ks * 32);
            short8 bfr = *reinterpret_cast<const short8*>(wrow + ks * 32);
            acc = mfma16(a2, bfr, acc);
        }
        float bb = b2f(b2v[col]);
        #pragma unroll
        for (int r = 0; r < 4; r++) {
            long o = (long)(row0 + quad * 4 + r) * 256 + col;
            store_any(out, o, fdt, x[o] + acc[r] + bb);
        }
    }
}

// ---------------- Temporal sampling (8 q/block, 8 ch/thread, conditional corners) ----------------
__global__ __launch_bounds__(256) void temporal_kernel(const bf16* __restrict__ ai,
                                                       const bf16* __restrict__ toffB,
                                                       const bf16* __restrict__ twlB,
                                                       const void* __restrict__ ref2d,
                                                       const void* __restrict__ ego,
                                                       const int* __restrict__ flags,
                                                       bf16* __restrict__ tfB) {
    int tid = threadIdx.x;
    int ql = tid >> 5, t = tid & 31;
    int g = t >> 2, q4 = t & 3;
    long n0 = (long)blockIdx.x * 8;
    __shared__ float s_toff[8][8][17];
    __shared__ float s_twl[8][64];
    __shared__ float s_base[8][4];
    for (int i = tid; i < 8 * 128; i += 256) {
        int q = i >> 7, j = i & 127;
        int si = j >> 6, r = j & 63, gg = r >> 3, w = r & 7;
        s_toff[q][gg][si * 8 + w] = b2f(toffB[n0 * 128 + i]);
    }
    for (int i = tid; i < 8 * 64; i += 256) s_twl[i >> 6][i & 63] = b2f(twlB[n0 * 64 + i]);
    if (tid < 8) {
        int f = flags[0];
        float rx = load_any(ref2d, (n0 + tid) * 2, f), ry = load_any(ref2d, (n0 + tid) * 2 + 1, f);
        s_base[tid][0] = rx + load_any(ego, 0, f); s_base[tid][1] = ry + load_any(ego, 1, f);
        s_base[tid][2] = rx;                       s_base[tid][3] = ry;
    }
    __syncthreads();
    float acc[8];
    #pragma unroll
    for (int i = 0; i < 8; i++) acc[i] = 0.f;
    int choff = g * 32 + q4 * 8;
    #pragma unroll
    for (int si = 0; si < 2; si++) {
        float l0 = s_twl[ql][si * 32 + g * 4 + 0], l1 = s_twl[ql][si * 32 + g * 4 + 1];
        float l2 = s_twl[ql][si * 32 + g * 4 + 2], l3 = s_twl[ql][si * 32 + g * 4 + 3];
        float mx = fmaxf(fmaxf(l0, l1), fmaxf(l2, l3));
        float e0 = __expf(l0 - mx), e1 = __expf(l1 - mx);
        float e2 = __expf(l2 - mx), e3 = __expf(l3 - mx);
        float inv = 1.f / (e0 + e1 + e2 + e3);
        float wts[4] = {e0 * inv, e1 * inv, e2 * inv, e3 * inv};
        int aoff = si * 256;
        float bx = s_base[ql][si * 2], by = s_base[ql][si * 2 + 1];
        #pragma unroll
        for (int pt = 0; pt < 4; pt++) {
            float u = bx + s_toff[ql][g][si * 8 + pt * 2 + 0];
            float v = by + s_toff[ql][g][si * 8 + pt * 2 + 1];
            float ix = u * (float)BW - 0.5f;
            float iy = v * (float)BH - 0.5f;
            float x0f = floorf(ix), y0f = floorf(iy);
            int x0 = (int)x0f, y0 = (int)y0f;
            float wx1 = ix - x0f, wy1 = iy - y0f;
            float wx0 = 1.f - wx1, wy0 = 1.f - wy1;
            #pragma unroll
            for (int cy = 0; cy < 2; cy++) {
                int yy = y0 + cy;
                if ((unsigned)yy >= BH) continue;
                float wy = cy ? wy1 : wy0;
                #pragma unroll
                for (int cx = 0; cx < 2; cx++) {
                    int xx = x0 + cx;
                    if ((unsigned)xx >= BW) continue;
                    float wq = wts[pt] * wy * (cx ? wx1 : wx0);
                    uint4 uu = *reinterpret_cast<const uint4*>(
                        ai + (long)(yy * BW + xx) * 512 + aoff + choff);
                    acc[0] += wq * __uint_as_float(uu.x << 16);
                    acc[1] += wq * __uint_as_float(uu.x & 0xFFFF0000u);
                    acc[2] += wq * __uint_as_float(uu.y << 16);
                    acc[3] += wq * __uint_as_float(uu.y & 0xFFFF0000u);
                    acc[4] += wq * __uint_as_float(uu.z << 16);
                    acc[5] += wq * __uint_as_float(uu.z & 0xFFFF0000u);
                    acc[6] += wq * __uint_as_float(uu.w << 16);
                    acc[7] += wq * __uint_as_float(uu.w & 0xFFFF0000u);
                }
            }
        }
    }
    uint4 o;
    o.x = pack2(acc[0] * 0.5f, acc[1] * 0.5f);
    o.y = pack2(acc[2] * 0.5f, acc[3] * 0.5f);
    o.z = pack2(acc[4] * 0.5f, acc[5] * 0.5f);
    o.w = pack2(acc[6] * 0.5f, acc[7] * 0.5f);
    *reinterpret_cast<uint4*>(tfB + (n0 + ql) * 256 + choff) = o;
}

// ---------------- Spatial v5: conditional corners + hoisted softmax numerators ----------------
__global__ __launch_bounds__(128) void spatial_kernel(const bf16* __restrict__ soffB,
                                                      const bf16* __restrict__ swlB,
                                                      const void* __restrict__ refcam,
                                                      const void* __restrict__ bmask,
                                                      const bf16* __restrict__ imgT,
                                                      const void* __restrict__ img_raw,
                                                      int use_imgT,
                                                      const int* __restrict__ flags,
                                                      bf16* __restrict__ sfB) {
    int tid = threadIdx.x;
    int ql = tid >> 5, t = tid & 31;
    int g = t >> 2, q4 = t & 3;
    long n0 = (long)blockIdx.x * 4;
    __shared__ float s_soff[4][8][33];
    __shared__ float s_swl[4][144];        // [q][j*9 + g]
    __shared__ float s_ref[4][NC][PP][2];
    __shared__ int   s_vis[4][NC][PP];
    for (int i = tid; i < 4 * 256; i += 128) {
        int q = i >> 8, j = i & 255;
        s_soff[q][j >> 5][j & 31] = b2f(soffB[n0 * 256 + i]);
    }
    for (int i = tid; i < 4 * 128; i += 128) {
        int q = i >> 7, jr = i & 127;
        int gg = jr >> 4, j = jr & 15;
        s_swl[q][j * 9 + gg] = b2f(swlB[n0 * 128 + i]);
    }
    int fdt = flags[0], msz = flags[1];
    for (int i = tid; i < 4 * 48; i += 128) {
        int q = i / 48, r = i % 48;
        s_ref[q][r >> 3][(r & 7) >> 1][r & 1] =
            load_any(refcam, ((long)(r >> 3) * N_Q + n0 + q) * 8 + (r & 7), fdt);
    }
    if (tid < 4 * 24) {
        int q = tid / 24, r = tid % 24; int c = r >> 2, p = r & 3;
        long idx = ((long)c * N_Q + n0 + q) * 4 + p;
        int v;
        if (msz == 1)      v = ((const unsigned char*)bmask)[idx] != 0;
        else if (msz == 2) v = ((const unsigned short*)bmask)[idx] != 0;
        else if (msz == 4) v = ((const unsigned int*)bmask)[idx] != 0u;
        else               v = ((const unsigned long long*)bmask)[idx] != 0ULL;
        s_vis[q][c][p] = v;
    }
    __syncthreads();
    // hoisted softmax numerators: exp(l_j - global_max), computed ONCE per thread.
    // Masked softmax over any subset is shift-invariant, so the per-cam weights are
    // ew[j]*vis / sum(ew*vis) — no per-cam exp needed.
    float ew[16];
    {
        float lw[16], mx = -3e38f;
        #pragma unroll
        for (int j = 0; j < 16; j++) { lw[j] = s_swl[ql][j * 9 + g]; mx = fmaxf(mx, lw[j]); }
        #pragma unroll
        for (int j = 0; j < 16; j++) ew[j] = __expf(lw[j] - mx);
    }
    float acc[8];
    #pragma unroll
    for (int i = 0; i < 8; i++) acc[i] = 0.f;
    float cnt = 0.f;
    int choff = g * 32 + q4 * 8;
    for (int c = 0; c < NC; c++) {
        int m0 = s_vis[ql][c][0], m1 = s_vis[ql][c][1];
        int m2 = s_vis[ql][c][2], m3 = s_vis[ql][c][3];
        if (!(m0 | m1 | m2 | m3)) continue;
        cnt += 1.f;
        float sum = 0.f;
        #pragma unroll
        for (int j = 0; j < 16; j++)
            sum += s_vis[ql][c][j >> 2] ? ew[j] : 0.f;
        float inv = 1.f / fmaxf(sum, 1e-20f);
        const bf16* img = imgT + (long)c * HF * WF * 256 + choff;
        #pragma unroll
        for (int p = 0; p < PP; p++) {
            if (!s_vis[ql][c][p]) continue;
            float rx = s_ref[ql][c][p][0], ry = s_ref[ql][c][p][1];
            #pragma unroll
            for (int s = 0; s < PS; s++) {
                float wi = ew[p * 4 + s] * inv;
                float u = rx + s_soff[ql][g][p * 8 + s * 2 + 0];
                float v = ry + s_soff[ql][g][p * 8 + s * 2 + 1];
                float ix = u * (float)WF - 0.5f, iy = v * (float)HF - 0.5f;
                float x0f = floorf(ix), y0f = floorf(iy);
                int x0 = (int)x0f, y0 = (int)y0f;
                float wx1 = ix - x0f, wy1 = iy - y0f;
                float wx0 = 1.f - wx1, wy0 = 1.f - wy1;
                #pragma unroll
                for (int cy = 0; cy < 2; cy++) {
                    int yy = y0 + cy;
                    if ((unsigned)yy >= HF) continue;
                    float wy = cy ? wy1 : wy0;
                    #pragma unroll
                    for (int cx = 0; cx < 2; cx++) {
                        int xx = x0 + cx;
                        if ((unsigned)xx >= WF) continue;
                        float wq = wi * wy * (cx ? wx1 : wx0);
                        if (use_imgT) {
                            uint4 uu = *reinterpret_cast<const uint4*>(
                                img + (long)(yy * WF + xx) * 256);
                            acc[0] += wq * __uint_as_float(uu.x << 16);
                            acc[1] += wq * __uint_as_float(uu.x & 0xFFFF0000u);
                            acc[2] += wq * __uint_as_float(uu.y << 16);
                            acc[3] += wq * __uint_as_float(uu.y & 0xFFFF0000u);
                            acc[4] += wq * __uint_as_float(uu.z << 16);
                            acc[5] += wq * __uint_as_float(uu.z & 0xFFFF0000u);
                            acc[6] += wq * __uint_as_float(uu.w << 16);
                            acc[7] += wq * __uint_as_float(uu.w & 0xFFFF0000u);
                        } else {
                            #pragma unroll
                            for (int e = 0; e < 8; e++)
                                acc[e] += wq * load_any(img_raw,
                                    (((long)c * 256 + choff + e) * HF + yy) * WF + xx, fdt);
                        }
                    }
                }
            }
        }
    }
    float invc = 1.f / fmaxf(cnt, 1.f);
    uint4 o;
    o.x = pack2(acc[0] * invc, acc[1] * invc);
    o.y = pack2(acc[2] * invc, acc[3] * invc);
    o.z = pack2(acc[4] * invc, acc[5] * invc);
    o.w = pack2(acc[6] * invc, acc[7] * invc);
    *reinterpret_cast<uint4*>(sfB + (n0 + ql) * 256 + choff) = o;
}

// bf16 element offsets inside the weight region (matrices stored TRANSPOSED [J][K])
#define W_TOFF_W 0
#define W_TOFF_B 65536
#define W_TWT_W  65664
#define W_TWT_B  98432
#define W_TOUT_W 98496
#define W_TOUT_B 164032
#define W_SOFF_W 164288
#define W_SOFF_B 229824
#define W_SWT_W  230080
#define W_SWT_B  262848
#define W_SOUT_W 262976
#define W_SOUT_B 328512
#define W_FFN_W1 328768
#define W_FFN_B1 590912
#define W_FFN_W2 591936
#define W_FFN_B2 854080
#define W_LN1_G  854336
#define W_LN1_B  854592
#define W_LN2_G  854848
#define W_LN2_B  855104
#define W_LN3_G  855360
#define W_LN3_B  855616

// byte offsets in workspace (total ~35.6 MB)
#define OB_WGT   0
#define OB_FLAGS 1711744
#define OB_AI    1712640
#define OB_TF    11952640
#define OB_X     17072640
#define OB_T4    27312640
#define OB_IMG   31152640
#define WS_NEED_IMG 35576320ULL

extern "C" void kernel_launch(void* const* d_in, const int* in_sizes, int n_in,
                              void* d_out, int out_size, void* d_ws, size_t ws_size,
                              hipStream_t stream) {
    char* W8 = (char*)d_ws;
    bf16*  wgt   = (bf16*)(W8 + OB_WGT);
    int*   flags = (int*)(W8 + OB_FLAGS);
    bf16*  ai    = (bf16*)(W8 + OB_AI);                 // N x 512, pb | q1
    bf16*  q2B   = ai;                                  // N x 256 (after temporal)
    bf16*  sfB   = (bf16*)(W8 + OB_AI + 5120000);       // N x 256
    bf16*  tfB   = (bf16*)(W8 + OB_TF);                 // N x 256
    bf16*  soffB = tfB;                                 // N x 256 (after t_out gemm)
    float* x     = (float*)(W8 + OB_X);                 // N x 256 f32 trunk
    bf16*  toffB = (bf16*)(W8 + OB_T4);                 // N x 128
    bf16*  twlB  = (bf16*)(W8 + OB_T4 + 2560000);       // N x 64
    bf16*  swlB  = toffB;                               // N x 128 (after temporal)
    bf16*  imgT  = (bf16*)(W8 + OB_IMG);                // NC*HF*WF*256
    int use_imgT = (ws_size >= WS_NEED_IMG) ? 1 : 0;

    detect_kernel<<<1, 256, 0, stream>>>(d_in[22], d_in[28], flags);

    {   // unified prep: 8 transposes + 14 flat cvts + img transpose
        PrepDesc pd;
        const int tsrc[8] = {6, 8, 10, 12, 14, 16, 18, 20};
        const int toff[8] = {W_TOFF_W, W_TWT_W, W_TOUT_W, W_SOFF_W, W_SWT_W, W_SOUT_W,
                             W_FFN_W1, W_FFN_W2};
        const int tR[8] = {512, 512, 256, 256, 256, 256, 256, 1024};
        const int tC[8] = {128, 64, 256, 256, 128, 256, 1024, 256};
        const int fsrc[14] = {7, 9, 11, 13, 15, 17, 19, 21, 22, 23, 24, 25, 26, 27};
        const int foff[14] = {W_TOFF_B, W_TWT_B, W_TOUT_B, W_SOFF_B, W_SWT_B, W_SOUT_B,
                              W_FFN_B1, W_FFN_B2, W_LN1_G, W_LN1_B, W_LN2_G, W_LN2_B,
                              W_LN3_G, W_LN3_B};
        const int fcnt[14] = {128, 64, 256, 256, 128, 256, 1024, 256, 256, 256, 256, 256, 256, 256};
        int a = 0, blk = 0;
        for (int i = 0; i < 8; i++, a++) {
            pd.src[a] = d_in[tsrc[i]]; pd.dst_off[a] = toff[i];
            pd.count[a] = tR[i] * tC[i]; pd.R[a] = tR[i]; pd.C[a] = tC[i];
            pd.type[a] = 1; pd.blk_start[a] = blk; blk += (pd.count[a] + 255) / 256;
        }
        for (int i = 0; i < 14; i++, a++) {
            pd.src[a] = d_in[fsrc[i]]; pd.dst_off[a] = foff[i];
            pd.count[a] = fcnt[i]; pd.R[a] = 0; pd.C[a] = 0;
            pd.type[a] = 0; pd.blk_start[a] = blk; blk += (pd.count[a] + 255) / 256;
        }
        pd.src[a] = d_in[2]; pd.dst_off[a] = 0;
        pd.count[a] = use_imgT ? NC * HF * WF * 256 : 0;
        pd.R[a] = 0; pd.C[a] = 0; pd.type[a] = 2; pd.blk_start[a] = blk;
        blk += (pd.count[a] + 255) / 256;
        pd.blk_start[NP] = blk;
        prep_kernel<<<blk, 256, 0, stream>>>(pd, wgt, imgT, flags);
    }

    ln12_kernel<<<5000, 256, 0, stream>>>(d_in[1], d_in[0], flags,
                                          wgt + W_LN1_G, wgt + W_LN1_B, ai);
    gemm_dual<512, 128, 64><<<dim3(313, 3), 256, 0, stream>>>(ai,
        wgt + W_TOFF_W, wgt + W_TOFF_B, T_RAD, toffB,
        wgt + W_TWT_W, wgt + W_TWT_B, twlB);
    temporal_kernel<<<1250, 256, 0, stream>>>(ai, toffB, twlB, d_in[3], d_in[5], flags, tfB);
    gemm_mfma<256, 256, 2><<<dim3(313, 4), 256, 0, stream>>>(tfB, wgt + W_TOUT_W, wgt + W_TOUT_B,
        x, d_in[0], nullptr, flags);
    ln_kernel<<<2500, 256, 0, stream>>>(x, wgt + W_LN2_G, wgt + W_LN2_B, q2B);
    gemm_dual<256, 256, 128><<<dim3(313, 6), 256, 0, stream>>>(q2B,
        wgt + W_SOFF_W, wgt + W_SOFF_B, S_RAD, soffB,
        wgt + W_SWT_W, wgt + W_SWT_B, swlB);
    spatial_kernel<<<2500, 128, 0, stream>>>(soffB, swlB, d_in[4], d_in[28], imgT, d_in[2],
                                             use_imgT, flags, sfB);
    gemm_mfma<256, 256, 3><<<dim3(313, 4), 256, 0, stream>>>(sfB, wgt + W_SOUT_W, wgt + W_SOUT_B,
        x, nullptr, x, flags);
    ffn_mfma<<<625, 256, 0, stream>>>(x, wgt + W_LN3_G, wgt + W_LN3_B,
                                      wgt + W_FFN_W1, wgt + W_FFN_B1,
                                      wgt + W_FFN_W2, wgt + W_FFN_B2, d_out, flags);
}